// Round 1
// baseline (203.348 us; speedup 1.0000x reference)
//
#include <hip/hip_runtime.h>
#include <hip/hip_bf16.h>
#include <hip/hip_cooperative_groups.h>

namespace cg = cooperative_groups;

// Problem constants (fixed by reference):
//   B=16, L=512, D=C=F=256, K=3, M=2048, EPS=1e-5
#define Bn 16
#define Ln 512
#define Cn 256
#define Fn 256
#define Kn 3
#define Mn 2048

#define NKSTEP 24        // 768 / 32
#define MT 32            // L-rows per block -> 256 conv tiles (1 block/CU)
#define XS_PS 264        // LDS A-slab row stride (bf16 units); 528 B = 33*16

typedef __attribute__((ext_vector_type(8))) short short8;
typedef __attribute__((ext_vector_type(4))) float f32x4;

static __device__ __forceinline__ unsigned short f2bf(float f) {
    unsigned int u = __float_as_uint(f);
    return (unsigned short)((u + 0x7fff + ((u >> 16) & 1)) >> 16);   // RNE
}

// one length-regulate float4: out[e4] = (map>=0) ? x[b,map,:] : 0
// out f4-index == e4 because out is dense (B,M,C) and bm = e4>>6.
static __device__ __forceinline__ void gather_one(
    const float* __restrict__ gx, const int* __restrict__ gmap,
    float* __restrict__ gout, int e4)
{
    int d4 = e4 & 63;
    int bm = e4 >> 6;                 // b*Mn + m  (Mn = 2048, pow2)
    int b  = bm >> 11;
    int l  = gmap[bm];
    float4 val = make_float4(0.f, 0.f, 0.f, 0.f);
    if (l >= 0) val = *((const float4*)(gx + (size_t)(b * Ln + l) * Cn) + d4);
    ((float4*)gout)[e4] = val;
}

// ---------- fused conv1d(K=3,SAME) via MFMA + bias + LayerNorm + ReLU ----------
// 32 L-rows of one batch per block; 4 waves, wave = 2 m-tiles x 4 n-tiles.
// A-frag (16x16x32): A[m=lane&15][k=(lane>>4)*8+j]; C/D: col=lane&15, row=(lane>>4)*4+reg.
// LN done in register space from the accumulator. (Verified in prior session.)
template <bool IS_F32_IN, bool DO_LINEAR>
static __device__ __forceinline__ void conv_phase(
    const void* __restrict__ in_,               // (B,L,C) f32 or bf16
    const unsigned short* __restrict__ bp,      // packed weights (bf16 frag order)
    const float* __restrict__ bias,             // (F)
    const float* __restrict__ gamma,            // (F)
    const float* __restrict__ beta,             // (F)
    const float* __restrict__ lw,               // (F)  [DO_LINEAR]
    const float* __restrict__ lb,               // (1)  [DO_LINEAR]
    unsigned short* __restrict__ hout,          // bf16 (B,L,F) [!DO_LINEAR]
    float* __restrict__ dup,                    // (B,L)        [DO_LINEAR]
    int cblk, int t,
    unsigned short* xs, float2 (*red)[4], float (*red2)[4])
{
    const int b  = cblk >> 4;          // 16 l-tiles per batch
    const int l0 = (cblk & 15) * MT;

    // ---- stage input rows [l0-1, l0+32], zero-padded, as bf16 ----
    if (IS_F32_IN) {
        const float* in = (const float*)in_;
        for (int idx = t; idx < (MT + 2) * 64; idx += 256) {   // 64 float4 per row
            int row = idx >> 6;
            int c4  = (idx & 63) * 4;
            int l = l0 + row - 1;
            float4 v = make_float4(0.f, 0.f, 0.f, 0.f);
            if (l >= 0 && l < Ln) v = *(const float4*)&in[((size_t)b * Ln + l) * Cn + c4];
            unsigned int lo = (unsigned int)f2bf(v.x) | ((unsigned int)f2bf(v.y) << 16);
            unsigned int hi = (unsigned int)f2bf(v.z) | ((unsigned int)f2bf(v.w) << 16);
            *(uint2*)&xs[row * XS_PS + c4] = make_uint2(lo, hi);
        }
    } else {
        const unsigned short* in = (const unsigned short*)in_;
        for (int idx = t; idx < (MT + 2) * 32; idx += 256) {   // 32 x (8 bf16) per row
            int row = idx >> 5;
            int c8  = (idx & 31) * 8;
            int l = l0 + row - 1;
            uint4 v = make_uint4(0u, 0u, 0u, 0u);
            if (l >= 0 && l < Ln) v = *(const uint4*)&in[((size_t)b * Ln + l) * Cn + c8];
            *(uint4*)&xs[row * XS_PS + c8] = v;
        }
    }
    __syncthreads();

    const int lane = t & 63;
    const int wv   = t >> 6;      // n-group: cols wv*64 .. wv*64+63
    const int mrow = lane & 15;
    const int q    = lane >> 4;

    f32x4  acc[2][4] = {};
    short8 bfr[2][4];             // 2-slot ring, loaded 2 steps ahead
    short8 afr[2][2];

    auto loadB = [&](int s, int slot) {
        const unsigned short* p = bp + (size_t)((s * 16 + wv * 4) * 64 + lane) * 8;
        #pragma unroll
        for (int i = 0; i < 4; ++i)
            bfr[slot][i] = *(const short8*)(p + (size_t)i * 64 * 8);
    };
    auto loadA = [&](int s, int slot) {
        const int k    = s >> 3;
        const int dcol = (s & 7) * 32 + q * 8;
        #pragma unroll
        for (int mt = 0; mt < 2; ++mt)
            afr[slot][mt] = *(const short8*)&xs[(mt * 16 + mrow + k) * XS_PS + dcol];
    };

    loadB(0, 0); loadA(0, 0);
    loadB(1, 1); loadA(1, 1);

    #pragma unroll 2
    for (int s = 0; s < NKSTEP; ++s) {
        const int slot = s & 1;
        #pragma unroll
        for (int mt = 0; mt < 2; ++mt)
            #pragma unroll
            for (int i = 0; i < 4; ++i)
                acc[mt][i] = __builtin_amdgcn_mfma_f32_16x16x32_bf16(
                    afr[slot][mt], bfr[slot][i], acc[mt][i], 0, 0, 0);
        const int sn = (s + 2 < NKSTEP) ? (s + 2) : s;   // tail: harmless reload
        loadB(sn, slot);
        loadA(sn, slot);
    }

    // ---- epilogue: bias + LayerNorm from registers ----
    float gv[4], bv[4], lwv[4], biasv[4];
    #pragma unroll
    for (int i = 0; i < 4; ++i) {
        int col = wv * 64 + i * 16 + mrow;
        biasv[i] = bias[col];
        gv[i]    = gamma[col];
        bv[i]    = beta[col];
        if (DO_LINEAR) lwv[i] = lw[col];
    }
    #pragma unroll
    for (int mt = 0; mt < 2; ++mt)
        #pragma unroll
        for (int i = 0; i < 4; ++i)
            #pragma unroll
            for (int r = 0; r < 4; ++r)
                acc[mt][i][r] += biasv[i];

    // per-row partial sums over this wave's 64 cols
    #pragma unroll
    for (int mt = 0; mt < 2; ++mt)
        #pragma unroll
        for (int r = 0; r < 4; ++r) {
            float s  = acc[mt][0][r] + acc[mt][1][r] + acc[mt][2][r] + acc[mt][3][r];
            float sq = acc[mt][0][r] * acc[mt][0][r] + acc[mt][1][r] * acc[mt][1][r]
                     + acc[mt][2][r] * acc[mt][2][r] + acc[mt][3][r] * acc[mt][3][r];
            #pragma unroll
            for (int off = 1; off <= 8; off <<= 1) {
                s  += __shfl_xor(s,  off, 64);
                sq += __shfl_xor(sq, off, 64);
            }
            if (mrow == 0) red[mt * 16 + q * 4 + r][wv] = make_float2(s, sq);
        }
    __syncthreads();

    float muv[2][4], rsv[2][4];
    #pragma unroll
    for (int mt = 0; mt < 2; ++mt)
        #pragma unroll
        for (int r = 0; r < 4; ++r) {
            int row = mt * 16 + q * 4 + r;
            float2 p0 = red[row][0], p1 = red[row][1], p2 = red[row][2], p3 = red[row][3];
            float s  = p0.x + p1.x + p2.x + p3.x;
            float sq = p0.y + p1.y + p2.y + p3.y;
            float mu  = s * (1.f / 256.f);
            float var = sq * (1.f / 256.f) - mu * mu;
            muv[mt][r] = mu;
            rsv[mt][r] = rsqrtf(var + 1e-5f);
        }

    if (!DO_LINEAR) {
        #pragma unroll
        for (int mt = 0; mt < 2; ++mt)
            #pragma unroll
            for (int r = 0; r < 4; ++r) {
                int l = l0 + mt * 16 + q * 4 + r;
                size_t base = ((size_t)b * Ln + l) * Fn;
                #pragma unroll
                for (int i = 0; i < 4; ++i) {
                    float o = fmaxf((acc[mt][i][r] - muv[mt][r]) * rsv[mt][r] * gv[i] + bv[i], 0.f);
                    hout[base + wv * 64 + i * 16 + mrow] = f2bf(o);
                }
            }
    } else {
        #pragma unroll
        for (int mt = 0; mt < 2; ++mt)
            #pragma unroll
            for (int r = 0; r < 4; ++r) {
                float dot = 0.f;
                #pragma unroll
                for (int i = 0; i < 4; ++i) {
                    float o = fmaxf((acc[mt][i][r] - muv[mt][r]) * rsv[mt][r] * gv[i] + bv[i], 0.f);
                    dot += o * lwv[i];
                }
                #pragma unroll
                for (int off = 1; off <= 8; off <<= 1)
                    dot += __shfl_xor(dot, off, 64);
                if (mrow == 0) red2[mt * 16 + q * 4 + r][wv] = dot;
            }
        __syncthreads();
        if (t < MT) {
            float d = red2[t][0] + red2[t][1] + red2[t][2] + red2[t][3];
            dup[b * Ln + l0 + t] = fmaxf(d + lb[0], 0.f);
        }
    }
}

// ---------------- single cooperative kernel: pack+scan | conv1+gather | conv2 ----------------
__global__ __launch_bounds__(256) void fused(
    const float* __restrict__ x, const int* __restrict__ target,
    const float* __restrict__ c1w, const float* __restrict__ c1b,
    const float* __restrict__ g1,  const float* __restrict__ be1,
    const float* __restrict__ c2w, const float* __restrict__ c2b,
    const float* __restrict__ g2,  const float* __restrict__ be2,
    const float* __restrict__ lw,  const float* __restrict__ lb,
    unsigned short* __restrict__ bp1, unsigned short* __restrict__ bp2,
    unsigned short* __restrict__ h1,  int* __restrict__ map,
    float* __restrict__ out, float* __restrict__ out_dup)
{
    __shared__ __align__(16) unsigned short xs[(MT + 2) * XS_PS];  // ~18 KB
    __shared__ float2 red[MT][4];                                  // 1 KB
    __shared__ float  red2[MT][4];                                 // 0.5 KB
    __shared__ int    ss[256];                                     // 1 KB

    const int blk = blockIdx.x;     // grid = exactly 256
    const int t   = threadIdx.x;
    cg::grid_group grid = cg::this_grid();

    // ---------------- Phase A: duration scan (blk 0..15) + weight pack (blk 16..207) ----------------
    if (blk < 16) {
        const int bb = blk;
        int v0 = target[bb * Ln + 2 * t];
        int v1 = target[bb * Ln + 2 * t + 1];
        ss[t] = v0 + v1;
        __syncthreads();
        for (int off = 1; off < 256; off <<= 1) {
            int add = (t >= off) ? ss[t - off] : 0;
            __syncthreads();
            ss[t] += add;
            __syncthreads();
        }
        int S     = ss[t];        // inclusive pair-scan -> cumsum at 2t+1
        int total = ss[255];
        int cs1   = S;
        int cs0   = S - v1;
        int prev0 = cs0 - v0;
        for (int m = prev0; m < cs0; ++m) map[bb * Mn + m] = 2 * t;
        for (int m = cs0;   m < cs1; ++m) map[bb * Mn + m] = 2 * t + 1;
        for (int m = total + t; m < Mn; m += 256) map[bb * Mn + m] = -1;
    } else if (blk < 208) {
        // pack: one short8 (contiguous dest) per thread; 192*256 = 49152 units total.
        // unit v: lane=v&63, nt=(v>>6)&15, s=v>>10; j=0..7 share k, d consecutive.
        int v = (blk - 16) * 256 + t;
        const float* w = c1w;
        unsigned short* bp = bp1;
        if (v >= 24576) { v -= 24576; w = c2w; bp = bp2; }
        int lane = v & 63, nt = (v >> 6) & 15, s = v >> 10;
        int f    = nt * 16 + (lane & 15);
        int kap0 = s * 32 + (lane >> 4) * 8;          // 8-aligned -> k fixed over j
        const float* p = w + ((size_t)f * Cn + (kap0 & 255)) * Kn + (kap0 >> 8);
        short8 o;
        #pragma unroll
        for (int j = 0; j < 8; ++j) o[j] = (short)f2bf(p[3 * j]);
        *(short8*)(bp + (size_t)v * 8) = o;
    }
    // blocks 208..255 idle in phase A (phase A is ~2 us total)

    grid.sync();   // pack -> conv1, scan -> gather

    // ---------------- Phase B: conv1 (all 256 blocks), then length-regulate gather ----------------
    conv_phase<true, false>(x, bp1, c1b, g1, be1, nullptr, nullptr, h1, nullptr,
                            blk, t, xs, red, red2);
    {
        const int base = blk * 256 + t;               // 0..65535
        #pragma unroll 4
        for (int i = 0; i < 32; ++i)                  // 32 * 65536 = Bn*Mn*Cn/4
            gather_one(x, map, out, base + i * 65536);
    }

    grid.sync();   // h1 (incl. neighbor-tile halo rows) -> conv2

    // ---------------- Phase C: conv2 + fused linear head ----------------
    conv_phase<false, true>(h1, bp2, c2b, g2, be2, lw, lb, nullptr, out_dup,
                            blk, t, xs, red, red2);
}

extern "C" void kernel_launch(void* const* d_in, const int* in_sizes, int n_in,
                              void* d_out, int out_size, void* d_ws, size_t ws_size,
                              hipStream_t stream) {
    const float* x    = (const float*)d_in[0];
    const int*   targ = (const int*)d_in[1];
    // d_in[2] = mel_max_length (scalar) = 2048, hardcoded
    const float* c1w = (const float*)d_in[3];
    const float* c1b = (const float*)d_in[4];
    const float* g1  = (const float*)d_in[5];
    const float* be1 = (const float*)d_in[6];
    const float* c2w = (const float*)d_in[7];
    const float* c2b = (const float*)d_in[8];
    const float* g2  = (const float*)d_in[9];
    const float* be2 = (const float*)d_in[10];
    const float* lw  = (const float*)d_in[11];
    const float* lb  = (const float*)d_in[12];

    float* out     = (float*)d_out;                       // (B,M,C)
    float* out_dup = out + (size_t)Bn * Mn * Cn;          // (B,L)

    // workspace layout
    char* ws = (char*)d_ws;
    unsigned short* bp1 = (unsigned short*)ws;                       // 384 KiB
    unsigned short* bp2 = (unsigned short*)(ws + 393216);            // 384 KiB
    unsigned short* h1  = (unsigned short*)(ws + 2 * 393216);        // 4 MiB bf16
    int*            map = (int*)(ws + 2 * 393216 + 4194304);         // 128 KiB

    void* args[] = {
        (void*)&x, (void*)&targ,
        (void*)&c1w, (void*)&c1b, (void*)&g1, (void*)&be1,
        (void*)&c2w, (void*)&c2b, (void*)&g2, (void*)&be2,
        (void*)&lw, (void*)&lb,
        (void*)&bp1, (void*)&bp2, (void*)&h1, (void*)&map,
        (void*)&out, (void*)&out_dup
    };
    hipLaunchCooperativeKernel((const void*)fused, dim3(256), dim3(256),
                               args, 0, stream);
}

// Round 2
// 132.710 us; speedup vs baseline: 1.5323x; 1.5323x over previous
//
#include <hip/hip_runtime.h>
#include <hip/hip_bf16.h>

// Problem constants (fixed by reference):
//   B=16, L=512, D=C=F=256, K=3, M=2048, EPS=1e-5
#define Bn 16
#define Ln 512
#define Cn 256
#define Fn 256
#define Kn 3
#define Mn 2048

#define NKSTEP 24        // 768 / 32
#define MT 32            // output L-rows per conv block -> 256 conv blocks
#define XS_PS 264        // LDS slab row stride (bf16 units); 528 B = 33*16
#define XROWS 50         // staged x rows: global l0-9 .. l0+40
#define HROWS 48         // conv1 computed h rows: global l0-8 .. l0+39 (3 m-tiles)
#define HOFF  8          // h local row j <-> global l0 - HOFF + j
#define NCONVBLK 256

typedef __attribute__((ext_vector_type(8))) short short8;
typedef __attribute__((ext_vector_type(4))) float f32x4;

static __device__ __forceinline__ unsigned short f2bf(float f) {
    unsigned int u = __float_as_uint(f);
    return (unsigned short)((u + 0x7fff + ((u >> 16) & 1)) >> 16);   // RNE
}

// ---------- K1: weight pack (vectorized short8 dest) + duration scan ----------
// blocks 0..15: per-batch cumsum of target -> m->l map (-1 = zero-fill).
// blocks 16..207: pack. bp[((s*16+nt)*64+lane)*8+j] = w[f=nt*16+(lane&15)][d][k],
//   kappa = k*256+d = s*32 + (lane>>4)*8 + j.  One contiguous short8 per thread.
__global__ __launch_bounds__(256) void pack_scan(
    const float* __restrict__ w1, const float* __restrict__ w2,
    unsigned short* __restrict__ bp1, unsigned short* __restrict__ bp2,
    const int* __restrict__ target, int* __restrict__ map)
{
    __shared__ int ss[256];
    const int blk = blockIdx.x;
    const int t = threadIdx.x;
    if (blk < 16) {
        const int bb = blk;
        int v0 = target[bb * Ln + 2 * t];
        int v1 = target[bb * Ln + 2 * t + 1];
        ss[t] = v0 + v1;
        __syncthreads();
        for (int off = 1; off < 256; off <<= 1) {
            int add = (t >= off) ? ss[t - off] : 0;
            __syncthreads();
            ss[t] += add;
            __syncthreads();
        }
        int S     = ss[t];        // inclusive pair-scan -> cumsum at 2t+1
        int total = ss[255];
        int cs1   = S;
        int cs0   = S - v1;
        int prev0 = cs0 - v0;
        for (int m = prev0; m < cs0; ++m) map[bb * Mn + m] = 2 * t;
        for (int m = cs0;   m < cs1; ++m) map[bb * Mn + m] = 2 * t + 1;
        for (int m = total + t; m < Mn; m += 256) map[bb * Mn + m] = -1;
    } else {
        // 192 blocks * 256 threads = 49152 short8 units (24576 per conv)
        int v = (blk - 16) * 256 + t;
        const float* w = w1;
        unsigned short* bp = bp1;
        if (v >= 24576) { v -= 24576; w = w2; bp = bp2; }
        int lane = v & 63, nt = (v >> 6) & 15, s = v >> 10;
        int f    = nt * 16 + (lane & 15);
        int kap0 = s * 32 + (lane >> 4) * 8;          // 8-aligned -> k fixed over j
        const float* p = w + ((size_t)f * Cn + (kap0 & 255)) * Kn + (kap0 >> 8);
        short8 o;
        #pragma unroll
        for (int j = 0; j < 8; ++j) o[j] = (short)f2bf(p[3 * j]);
        *(short8*)(bp + (size_t)v * 8) = o;
    }
}

// ---------- K2: fused conv1(48 rows, halo recompute) -> LDS -> conv2 + linear head,
//                plus length-regulate gather on independent blocks ----------
// Conv blocks (0..255): 32 output rows of one batch; 4 waves; wave = m-tiles x 4 n-tiles.
// A-frag (16x16x32): A[m=lane&15][k=(lane>>4)*8+j]; C/D: col=lane&15, row=(lane>>4)*4+reg.
// conv1 computes h rows l0-8..l0+39 (garbage outside [l0-1,l0+32] never read by conv2).
// h kept in LDS (aliases xs after conv1 reads complete) -> no global h round-trip.
__global__ __launch_bounds__(256, 4) void conv12_gather(
    const float* __restrict__ x,                // (B,L,C) f32
    const unsigned short* __restrict__ bp1,     // packed conv1 weights
    const unsigned short* __restrict__ bp2,     // packed conv2 weights
    const float* __restrict__ c1b, const float* __restrict__ g1, const float* __restrict__ be1,
    const float* __restrict__ c2b, const float* __restrict__ g2, const float* __restrict__ be2,
    const float* __restrict__ lw,  const float* __restrict__ lb,
    const int* __restrict__ gmap,               // (B,M)
    float* __restrict__ out,                    // (B,M,C)
    float* __restrict__ dup)                    // (B,L)
{
    __shared__ __align__(16) unsigned short xs[XROWS * XS_PS];  // 26.4 KB; h aliases rows 0..47
    __shared__ float2 red[HROWS][4];                            // 1.5 KB
    __shared__ float  red2[MT][4];                              // 0.5 KB

    const int t = threadIdx.x;

    if (blockIdx.x >= NCONVBLK) {
        // ---- length-regulate gather: out[b,m,:] = (map>=0) ? x[b,map,:] : 0 ----
        int e4 = (blockIdx.x - NCONVBLK) * 256 + t;   // float4 index
        int d4 = e4 & 63;
        int bm = e4 >> 6;
        int b  = bm >> 11;
        int l  = gmap[bm];
        float4 val = make_float4(0.f, 0.f, 0.f, 0.f);
        if (l >= 0) val = *((const float4*)(x + (size_t)(b * Ln + l) * Cn) + d4);
        ((float4*)out)[e4] = val;
        return;
    }

    const int b  = blockIdx.x >> 4;          // 16 l-tiles per batch
    const int l0 = (blockIdx.x & 15) * MT;

    // ---- stage x rows l0-9 .. l0+40, zero-padded, as bf16 ----
    for (int idx = t; idx < XROWS * 64; idx += 256) {   // 64 float4 per row
        int row = idx >> 6;
        int c4  = (idx & 63) * 4;
        int l = l0 - 9 + row;
        float4 v = make_float4(0.f, 0.f, 0.f, 0.f);
        if (l >= 0 && l < Ln) v = *(const float4*)&x[((size_t)b * Ln + l) * Cn + c4];
        unsigned int lo = (unsigned int)f2bf(v.x) | ((unsigned int)f2bf(v.y) << 16);
        unsigned int hi = (unsigned int)f2bf(v.z) | ((unsigned int)f2bf(v.w) << 16);
        *(uint2*)&xs[row * XS_PS + c4] = make_uint2(lo, hi);
    }
    __syncthreads();

    const int lane = t & 63;
    const int wv   = t >> 6;      // n-group: cols wv*64 .. wv*64+63
    const int mrow = lane & 15;
    const int q    = lane >> 4;

    // ================= conv1: 3 m-tiles (h rows l0-8 .. l0+39) =================
    f32x4  acc1[3][4] = {};
    short8 bfr[2][4];             // 2-slot ring, loaded 2 steps ahead
    short8 afr[2][3];

    auto loadB1 = [&](int s, int slot) {
        const unsigned short* p = bp1 + (size_t)((s * 16 + wv * 4) * 64 + lane) * 8;
        #pragma unroll
        for (int i = 0; i < 4; ++i)
            bfr[slot][i] = *(const short8*)(p + (size_t)i * 64 * 8);
    };
    // h local row jr reads x global (l0-8+jr)-1+k  <->  xs row jr + k
    auto loadA1 = [&](int s, int slot) {
        const int k    = s >> 3;
        const int dcol = (s & 7) * 32 + q * 8;
        #pragma unroll
        for (int mt = 0; mt < 3; ++mt)
            afr[slot][mt] = *(const short8*)&xs[(mt * 16 + mrow + k) * XS_PS + dcol];
    };

    loadB1(0, 0); loadA1(0, 0);
    loadB1(1, 1); loadA1(1, 1);

    #pragma unroll 2
    for (int s = 0; s < NKSTEP; ++s) {
        const int slot = s & 1;
        #pragma unroll
        for (int mt = 0; mt < 3; ++mt)
            #pragma unroll
            for (int i = 0; i < 4; ++i)
                acc1[mt][i] = __builtin_amdgcn_mfma_f32_16x16x32_bf16(
                    afr[slot][mt], bfr[slot][i], acc1[mt][i], 0, 0, 0);
        const int sn = (s + 2 < NKSTEP) ? (s + 2) : s;   // tail: harmless reload
        loadB1(sn, slot);
        loadA1(sn, slot);
    }

    // ---- epilogue 1: bias + LayerNorm stats (48 rows) ----
    {
        float gv[4], bv[4], biasv[4];
        #pragma unroll
        for (int i = 0; i < 4; ++i) {
            int col = wv * 64 + i * 16 + mrow;
            biasv[i] = c1b[col];
            gv[i]    = g1[col];
            bv[i]    = be1[col];
        }
        #pragma unroll
        for (int mt = 0; mt < 3; ++mt)
            #pragma unroll
            for (int i = 0; i < 4; ++i)
                #pragma unroll
                for (int r = 0; r < 4; ++r)
                    acc1[mt][i][r] += biasv[i];

        #pragma unroll
        for (int mt = 0; mt < 3; ++mt)
            #pragma unroll
            for (int r = 0; r < 4; ++r) {
                float s  = acc1[mt][0][r] + acc1[mt][1][r] + acc1[mt][2][r] + acc1[mt][3][r];
                float sq = acc1[mt][0][r] * acc1[mt][0][r] + acc1[mt][1][r] * acc1[mt][1][r]
                         + acc1[mt][2][r] * acc1[mt][2][r] + acc1[mt][3][r] * acc1[mt][3][r];
                #pragma unroll
                for (int off = 1; off <= 8; off <<= 1) {
                    s  += __shfl_xor(s,  off, 64);
                    sq += __shfl_xor(sq, off, 64);
                }
                if (mrow == 0) red[mt * 16 + q * 4 + r][wv] = make_float2(s, sq);
            }
        __syncthreads();   // also guarantees all xs reads (conv1 MFMA) are done

        float muv[3][4], rsv[3][4];
        #pragma unroll
        for (int mt = 0; mt < 3; ++mt)
            #pragma unroll
            for (int r = 0; r < 4; ++r) {
                int row = mt * 16 + q * 4 + r;
                float2 p0 = red[row][0], p1 = red[row][1], p2 = red[row][2], p3 = red[row][3];
                float s  = p0.x + p1.x + p2.x + p3.x;
                float sq = p0.y + p1.y + p2.y + p3.y;
                float mu  = s * (1.f / 256.f);
                float var = sq * (1.f / 256.f) - mu * mu;
                muv[mt][r] = mu;
                rsv[mt][r] = rsqrtf(var + 1e-5f);
            }

        // ---- write h = relu(LN(conv1)) into LDS (aliases xs rows 0..47) ----
        // zero rows whose global l is out of [0,Ln) (conv2 SAME-pad boundary)
        #pragma unroll
        for (int mt = 0; mt < 3; ++mt)
            #pragma unroll
            for (int r = 0; r < 4; ++r) {
                int jr = mt * 16 + q * 4 + r;
                int l  = l0 - HOFF + jr;
                bool ok = (l >= 0 && l < Ln);
                #pragma unroll
                for (int i = 0; i < 4; ++i) {
                    float o = ok ? fmaxf((acc1[mt][i][r] - muv[mt][r]) * rsv[mt][r] * gv[i] + bv[i], 0.f)
                                 : 0.f;
                    xs[jr * XS_PS + (wv * 64 + i * 16 + mrow)] = f2bf(o);
                }
            }
    }
    __syncthreads();

    // ================= conv2: 2 m-tiles (output rows l0 .. l0+31) =================
    f32x4  acc2[2][4] = {};
    short8 afr2[2][2];

    auto loadB2 = [&](int s, int slot) {
        const unsigned short* p = bp2 + (size_t)((s * 16 + wv * 4) * 64 + lane) * 8;
        #pragma unroll
        for (int i = 0; i < 4; ++i)
            bfr[slot][i] = *(const short8*)(p + (size_t)i * 64 * 8);
    };
    // output row j reads h global l0+j-1+k <-> hs row j+k+HOFF-1 = j+k+7
    auto loadA2 = [&](int s, int slot) {
        const int k    = s >> 3;
        const int dcol = (s & 7) * 32 + q * 8;
        #pragma unroll
        for (int mt = 0; mt < 2; ++mt)
            afr2[slot][mt] = *(const short8*)&xs[(mt * 16 + mrow + k + 7) * XS_PS + dcol];
    };

    loadB2(0, 0); loadA2(0, 0);
    loadB2(1, 1); loadA2(1, 1);

    #pragma unroll 2
    for (int s = 0; s < NKSTEP; ++s) {
        const int slot = s & 1;
        #pragma unroll
        for (int mt = 0; mt < 2; ++mt)
            #pragma unroll
            for (int i = 0; i < 4; ++i)
                acc2[mt][i] = __builtin_amdgcn_mfma_f32_16x16x32_bf16(
                    afr2[slot][mt], bfr[slot][i], acc2[mt][i], 0, 0, 0);
        const int sn = (s + 2 < NKSTEP) ? (s + 2) : s;
        loadB2(sn, slot);
        loadA2(sn, slot);
    }

    // ---- epilogue 2: bias + LN + ReLU + linear head -> dup ----
    {
        float gv[4], bv[4], biasv[4], lwv[4];
        #pragma unroll
        for (int i = 0; i < 4; ++i) {
            int col = wv * 64 + i * 16 + mrow;
            biasv[i] = c2b[col];
            gv[i]    = g2[col];
            bv[i]    = be2[col];
            lwv[i]   = lw[col];
        }
        #pragma unroll
        for (int mt = 0; mt < 2; ++mt)
            #pragma unroll
            for (int i = 0; i < 4; ++i)
                #pragma unroll
                for (int r = 0; r < 4; ++r)
                    acc2[mt][i][r] += biasv[i];

        #pragma unroll
        for (int mt = 0; mt < 2; ++mt)
            #pragma unroll
            for (int r = 0; r < 4; ++r) {
                float s  = acc2[mt][0][r] + acc2[mt][1][r] + acc2[mt][2][r] + acc2[mt][3][r];
                float sq = acc2[mt][0][r] * acc2[mt][0][r] + acc2[mt][1][r] * acc2[mt][1][r]
                         + acc2[mt][2][r] * acc2[mt][2][r] + acc2[mt][3][r] * acc2[mt][3][r];
                #pragma unroll
                for (int off = 1; off <= 8; off <<= 1) {
                    s  += __shfl_xor(s,  off, 64);
                    sq += __shfl_xor(sq, off, 64);
                }
                if (mrow == 0) red[mt * 16 + q * 4 + r][wv] = make_float2(s, sq);
            }
        __syncthreads();

        float muv[2][4], rsv[2][4];
        #pragma unroll
        for (int mt = 0; mt < 2; ++mt)
            #pragma unroll
            for (int r = 0; r < 4; ++r) {
                int row = mt * 16 + q * 4 + r;
                float2 p0 = red[row][0], p1 = red[row][1], p2 = red[row][2], p3 = red[row][3];
                float s  = p0.x + p1.x + p2.x + p3.x;
                float sq = p0.y + p1.y + p2.y + p3.y;
                float mu  = s * (1.f / 256.f);
                float var = sq * (1.f / 256.f) - mu * mu;
                muv[mt][r] = mu;
                rsv[mt][r] = rsqrtf(var + 1e-5f);
            }

        #pragma unroll
        for (int mt = 0; mt < 2; ++mt)
            #pragma unroll
            for (int r = 0; r < 4; ++r) {
                float dot = 0.f;
                #pragma unroll
                for (int i = 0; i < 4; ++i) {
                    float o = fmaxf((acc2[mt][i][r] - muv[mt][r]) * rsv[mt][r] * gv[i] + bv[i], 0.f);
                    dot += o * lwv[i];
                }
                #pragma unroll
                for (int off = 1; off <= 8; off <<= 1)
                    dot += __shfl_xor(dot, off, 64);
                if (mrow == 0) red2[mt * 16 + q * 4 + r][wv] = dot;
            }
        __syncthreads();
        if (t < MT) {
            float d = red2[t][0] + red2[t][1] + red2[t][2] + red2[t][3];
            dup[b * Ln + l0 + t] = fmaxf(d + lb[0], 0.f);
        }
    }
}

extern "C" void kernel_launch(void* const* d_in, const int* in_sizes, int n_in,
                              void* d_out, int out_size, void* d_ws, size_t ws_size,
                              hipStream_t stream) {
    const float* x    = (const float*)d_in[0];
    const int*   targ = (const int*)d_in[1];
    // d_in[2] = mel_max_length (scalar) = 2048, hardcoded
    const float* c1w = (const float*)d_in[3];
    const float* c1b = (const float*)d_in[4];
    const float* g1  = (const float*)d_in[5];
    const float* be1 = (const float*)d_in[6];
    const float* c2w = (const float*)d_in[7];
    const float* c2b = (const float*)d_in[8];
    const float* g2  = (const float*)d_in[9];
    const float* be2 = (const float*)d_in[10];
    const float* lw  = (const float*)d_in[11];
    const float* lb  = (const float*)d_in[12];

    float* out     = (float*)d_out;                       // (B,M,C)
    float* out_dup = out + (size_t)Bn * Mn * Cn;          // (B,L)

    // workspace layout (no h1 anymore)
    char* ws = (char*)d_ws;
    unsigned short* bp1 = (unsigned short*)ws;                       // 384 KiB
    unsigned short* bp2 = (unsigned short*)(ws + 393216);            // 384 KiB
    int*            map = (int*)(ws + 2 * 393216);                   // 128 KiB

    // K1: weight pack (192 blocks) + duration scan (16 blocks)
    pack_scan<<<208, 256, 0, stream>>>(c1w, c2w, bp1, bp2, targ, map);

    // K2: fused conv1+conv2+linear (blocks 0..255) + gather (blocks 256..8447)
    conv12_gather<<<NCONVBLK + (Bn * Mn * Cn / 4) / 256, 256, 0, stream>>>(
        x, bp1, bp2, c1b, g1, be1, c2b, g2, be2, lw, lb,
        map, out, out_dup);
}

// Round 3
// 126.131 us; speedup vs baseline: 1.6122x; 1.0522x over previous
//
#include <hip/hip_runtime.h>
#include <hip/hip_bf16.h>

// Problem constants (fixed by reference):
//   B=16, L=512, D=C=F=256, K=3, M=2048, EPS=1e-5
#define Bn 16
#define Ln 512
#define Cn 256
#define Fn 256
#define Kn 3
#define Mn 2048

#define NKSTEP 24        // 768 / 32
#define MT 32            // output L-rows per conv block -> 256 conv blocks
#define XS_PS 264        // LDS slab row stride (bf16 units); 528 B = 33*16
#define XROWS 50         // staged x rows: global l0-9 .. l0+40
#define HROWS 48         // conv1 computed h rows: global l0-8 .. l0+39 (3 m-tiles)
#define HOFF  8          // h local row j <-> global l0 - HOFF + j
#define NCONVBLK 256
#define NGATHERBLK 2048  // each thread: 4 float4  (2048*256*4 = B*M*C/4)

typedef __attribute__((ext_vector_type(8))) short short8;
typedef __attribute__((ext_vector_type(4))) float f32x4;

static __device__ __forceinline__ unsigned short f2bf(float f) {
    unsigned int u = __float_as_uint(f);
    return (unsigned short)((u + 0x7fff + ((u >> 16) & 1)) >> 16);   // RNE
}

// ---------- K1: weight pack (vectorized short8 dest) + duration scan ----------
// blocks 0..15: per-batch cumsum of target -> m->l map (-1 = zero-fill).
// blocks 16..207: pack. bp[((s*16+nt)*64+lane)*8+j] = w[f=nt*16+(lane&15)][d][k],
//   kappa = k*256+d = s*32 + (lane>>4)*8 + j.  One contiguous short8 per thread.
__global__ __launch_bounds__(256) void pack_scan(
    const float* __restrict__ w1, const float* __restrict__ w2,
    unsigned short* __restrict__ bp1, unsigned short* __restrict__ bp2,
    const int* __restrict__ target, int* __restrict__ map)
{
    __shared__ int ss[256];
    const int blk = blockIdx.x;
    const int t = threadIdx.x;
    if (blk < 16) {
        const int bb = blk;
        int v0 = target[bb * Ln + 2 * t];
        int v1 = target[bb * Ln + 2 * t + 1];
        ss[t] = v0 + v1;
        __syncthreads();
        for (int off = 1; off < 256; off <<= 1) {
            int add = (t >= off) ? ss[t - off] : 0;
            __syncthreads();
            ss[t] += add;
            __syncthreads();
        }
        int S     = ss[t];        // inclusive pair-scan -> cumsum at 2t+1
        int total = ss[255];
        int cs1   = S;
        int cs0   = S - v1;
        int prev0 = cs0 - v0;
        for (int m = prev0; m < cs0; ++m) map[bb * Mn + m] = 2 * t;
        for (int m = cs0;   m < cs1; ++m) map[bb * Mn + m] = 2 * t + 1;
        for (int m = total + t; m < Mn; m += 256) map[bb * Mn + m] = -1;
    } else {
        // 192 blocks * 256 threads = 49152 short8 units (24576 per conv)
        int v = (blk - 16) * 256 + t;
        const float* w = w1;
        unsigned short* bp = bp1;
        if (v >= 24576) { v -= 24576; w = w2; bp = bp2; }
        int lane = v & 63, nt = (v >> 6) & 15, s = v >> 10;
        int f    = nt * 16 + (lane & 15);
        int kap0 = s * 32 + (lane >> 4) * 8;          // 8-aligned -> k fixed over j
        const float* p = w + ((size_t)f * Cn + (kap0 & 255)) * Kn + (kap0 >> 8);
        short8 o;
        #pragma unroll
        for (int j = 0; j < 8; ++j) o[j] = (short)f2bf(p[3 * j]);
        *(short8*)(bp + (size_t)v * 8) = o;
    }
}

// ---------- K2: fused conv1(48 rows, halo recompute) -> LDS -> conv2 + linear head,
//                plus length-regulate gather on independent blocks ----------
// Conv blocks (0..255): 32 output rows of one batch; 4 waves; wave = m-tiles x 4 n-tiles.
// A-frag (16x16x32): A[m=lane&15][k=(lane>>4)*8+j]; C/D: col=lane&15, row=(lane>>4)*4+reg.
// conv1 computes h rows l0-8..l0+39 (garbage outside [l0-1,l0+32] never read by conv2).
// h kept in LDS (aliases xs after conv1 reads complete) -> no global h round-trip.
// NOTE: no min-waves launch bound — round-2's (256,4) forced a 128-reg budget and
// spilled ~14.6 MB/launch to scratch (WRITE_SIZE 48.2 vs 33.6 MB expected).
__global__ __launch_bounds__(256) void conv12_gather(
    const float* __restrict__ x,                // (B,L,C) f32
    const unsigned short* __restrict__ bp1,     // packed conv1 weights
    const unsigned short* __restrict__ bp2,     // packed conv2 weights
    const float* __restrict__ c1b, const float* __restrict__ g1, const float* __restrict__ be1,
    const float* __restrict__ c2b, const float* __restrict__ g2, const float* __restrict__ be2,
    const float* __restrict__ lw,  const float* __restrict__ lb,
    const int* __restrict__ gmap,               // (B,M)
    float* __restrict__ out,                    // (B,M,C)
    float* __restrict__ dup)                    // (B,L)
{
    __shared__ __align__(16) unsigned short xs[XROWS * XS_PS];  // 26.4 KB; h aliases rows 0..47
    __shared__ float2 red[HROWS][4];                            // 1.5 KB
    __shared__ float  red2[MT][4];                              // 0.5 KB

    const int t = threadIdx.x;

    if (blockIdx.x >= NCONVBLK) {
        // ---- length-regulate gather: out[b,m,:] = (map>=0) ? x[b,map,:] : 0 ----
        // 4 independent float4 per thread: batch the map loads, then the x loads,
        // then the stores (memory-level parallelism at low occupancy).
        const int base = (blockIdx.x - NCONVBLK) * 256 + t;   // 0 .. 524287
        int lv[4];
        #pragma unroll
        for (int i = 0; i < 4; ++i)
            lv[i] = gmap[(base + i * 524288) >> 6];
        float4 val[4];
        #pragma unroll
        for (int i = 0; i < 4; ++i) {
            int e4 = base + i * 524288;
            int d4 = e4 & 63;
            int b  = e4 >> 17;                 // bm>>11, bm=e4>>6
            val[i] = make_float4(0.f, 0.f, 0.f, 0.f);
            if (lv[i] >= 0)
                val[i] = *((const float4*)(x + (size_t)(b * Ln + lv[i]) * Cn) + d4);
        }
        #pragma unroll
        for (int i = 0; i < 4; ++i)
            ((float4*)out)[base + i * 524288] = val[i];
        return;
    }

    const int b  = blockIdx.x >> 4;          // 16 l-tiles per batch
    const int l0 = (blockIdx.x & 15) * MT;

    // ---- stage x rows l0-9 .. l0+40, zero-padded, as bf16 ----
    for (int idx = t; idx < XROWS * 64; idx += 256) {   // 64 float4 per row
        int row = idx >> 6;
        int c4  = (idx & 63) * 4;
        int l = l0 - 9 + row;
        float4 v = make_float4(0.f, 0.f, 0.f, 0.f);
        if (l >= 0 && l < Ln) v = *(const float4*)&x[((size_t)b * Ln + l) * Cn + c4];
        unsigned int lo = (unsigned int)f2bf(v.x) | ((unsigned int)f2bf(v.y) << 16);
        unsigned int hi = (unsigned int)f2bf(v.z) | ((unsigned int)f2bf(v.w) << 16);
        *(uint2*)&xs[row * XS_PS + c4] = make_uint2(lo, hi);
    }
    __syncthreads();

    const int lane = t & 63;
    const int wv   = t >> 6;      // n-group: cols wv*64 .. wv*64+63
    const int mrow = lane & 15;
    const int q    = lane >> 4;

    // ================= conv1: 3 m-tiles (h rows l0-8 .. l0+39) =================
    // single-buffered fragments (register pressure!): 48 acc + 16 B + 12 A regs
    f32x4  acc1[3][4] = {};
    {
        short8 bfr[4], afr[3];
        #pragma unroll 2
        for (int s = 0; s < NKSTEP; ++s) {
            const unsigned short* p = bp1 + (size_t)((s * 16 + wv * 4) * 64 + lane) * 8;
            #pragma unroll
            for (int i = 0; i < 4; ++i)
                bfr[i] = *(const short8*)(p + (size_t)i * 64 * 8);
            const int k    = s >> 3;
            const int dcol = (s & 7) * 32 + q * 8;
            #pragma unroll
            for (int mt = 0; mt < 3; ++mt)
                afr[mt] = *(const short8*)&xs[(mt * 16 + mrow + k) * XS_PS + dcol];
            #pragma unroll
            for (int mt = 0; mt < 3; ++mt)
                #pragma unroll
                for (int i = 0; i < 4; ++i)
                    acc1[mt][i] = __builtin_amdgcn_mfma_f32_16x16x32_bf16(
                        afr[mt], bfr[i], acc1[mt][i], 0, 0, 0);
        }
    }

    // ---- epilogue 1: bias + LayerNorm stats (48 rows) ----
    {
        float gv[4], bv[4], biasv[4];
        #pragma unroll
        for (int i = 0; i < 4; ++i) {
            int col = wv * 64 + i * 16 + mrow;
            biasv[i] = c1b[col];
            gv[i]    = g1[col];
            bv[i]    = be1[col];
        }
        #pragma unroll
        for (int mt = 0; mt < 3; ++mt)
            #pragma unroll
            for (int i = 0; i < 4; ++i)
                #pragma unroll
                for (int r = 0; r < 4; ++r)
                    acc1[mt][i][r] += biasv[i];

        #pragma unroll
        for (int mt = 0; mt < 3; ++mt)
            #pragma unroll
            for (int r = 0; r < 4; ++r) {
                float s  = acc1[mt][0][r] + acc1[mt][1][r] + acc1[mt][2][r] + acc1[mt][3][r];
                float sq = acc1[mt][0][r] * acc1[mt][0][r] + acc1[mt][1][r] * acc1[mt][1][r]
                         + acc1[mt][2][r] * acc1[mt][2][r] + acc1[mt][3][r] * acc1[mt][3][r];
                #pragma unroll
                for (int off = 1; off <= 8; off <<= 1) {
                    s  += __shfl_xor(s,  off, 64);
                    sq += __shfl_xor(sq, off, 64);
                }
                if (mrow == 0) red[mt * 16 + q * 4 + r][wv] = make_float2(s, sq);
            }
        __syncthreads();   // also guarantees all xs reads (conv1 A-frags) are done

        float muv[3][4], rsv[3][4];
        #pragma unroll
        for (int mt = 0; mt < 3; ++mt)
            #pragma unroll
            for (int r = 0; r < 4; ++r) {
                int row = mt * 16 + q * 4 + r;
                float2 p0 = red[row][0], p1 = red[row][1], p2 = red[row][2], p3 = red[row][3];
                float s  = p0.x + p1.x + p2.x + p3.x;
                float sq = p0.y + p1.y + p2.y + p3.y;
                float mu  = s * (1.f / 256.f);
                float var = sq * (1.f / 256.f) - mu * mu;
                muv[mt][r] = mu;
                rsv[mt][r] = rsqrtf(var + 1e-5f);
            }

        // ---- write h = relu(LN(conv1)) into LDS (aliases xs rows 0..47) ----
        // zero rows whose global l is out of [0,Ln) (conv2 SAME-pad boundary)
        #pragma unroll
        for (int mt = 0; mt < 3; ++mt)
            #pragma unroll
            for (int r = 0; r < 4; ++r) {
                int jr = mt * 16 + q * 4 + r;
                int l  = l0 - HOFF + jr;
                bool ok = (l >= 0 && l < Ln);
                #pragma unroll
                for (int i = 0; i < 4; ++i) {
                    float o = ok ? fmaxf((acc1[mt][i][r] - muv[mt][r]) * rsv[mt][r] * gv[i] + bv[i], 0.f)
                                 : 0.f;
                    xs[jr * XS_PS + (wv * 64 + i * 16 + mrow)] = f2bf(o);
                }
            }
    }
    __syncthreads();

    // ================= conv2: 2 m-tiles (output rows l0 .. l0+31) =================
    f32x4  acc2[2][4] = {};
    {
        short8 bfr[4], afr[2];
        #pragma unroll 2
        for (int s = 0; s < NKSTEP; ++s) {
            const unsigned short* p = bp2 + (size_t)((s * 16 + wv * 4) * 64 + lane) * 8;
            #pragma unroll
            for (int i = 0; i < 4; ++i)
                bfr[i] = *(const short8*)(p + (size_t)i * 64 * 8);
            const int k    = s >> 3;
            const int dcol = (s & 7) * 32 + q * 8;
            // output row j reads h global l0+j-1+k <-> h local row j+k+HOFF-1 = j+k+7
            #pragma unroll
            for (int mt = 0; mt < 2; ++mt)
                afr[mt] = *(const short8*)&xs[(mt * 16 + mrow + k + 7) * XS_PS + dcol];
            #pragma unroll
            for (int mt = 0; mt < 2; ++mt)
                #pragma unroll
                for (int i = 0; i < 4; ++i)
                    acc2[mt][i] = __builtin_amdgcn_mfma_f32_16x16x32_bf16(
                        afr[mt], bfr[i], acc2[mt][i], 0, 0, 0);
        }
    }

    // ---- epilogue 2: bias + LN + ReLU + linear head -> dup ----
    {
        float gv[4], bv[4], biasv[4], lwv[4];
        #pragma unroll
        for (int i = 0; i < 4; ++i) {
            int col = wv * 64 + i * 16 + mrow;
            biasv[i] = c2b[col];
            gv[i]    = g2[col];
            bv[i]    = be2[col];
            lwv[i]   = lw[col];
        }
        #pragma unroll
        for (int mt = 0; mt < 2; ++mt)
            #pragma unroll
            for (int i = 0; i < 4; ++i)
                #pragma unroll
                for (int r = 0; r < 4; ++r)
                    acc2[mt][i][r] += biasv[i];

        #pragma unroll
        for (int mt = 0; mt < 2; ++mt)
            #pragma unroll
            for (int r = 0; r < 4; ++r) {
                float s  = acc2[mt][0][r] + acc2[mt][1][r] + acc2[mt][2][r] + acc2[mt][3][r];
                float sq = acc2[mt][0][r] * acc2[mt][0][r] + acc2[mt][1][r] * acc2[mt][1][r]
                         + acc2[mt][2][r] * acc2[mt][2][r] + acc2[mt][3][r] * acc2[mt][3][r];
                #pragma unroll
                for (int off = 1; off <= 8; off <<= 1) {
                    s  += __shfl_xor(s,  off, 64);
                    sq += __shfl_xor(sq, off, 64);
                }
                if (mrow == 0) red[mt * 16 + q * 4 + r][wv] = make_float2(s, sq);
            }
        __syncthreads();

        float muv[2][4], rsv[2][4];
        #pragma unroll
        for (int mt = 0; mt < 2; ++mt)
            #pragma unroll
            for (int r = 0; r < 4; ++r) {
                int row = mt * 16 + q * 4 + r;
                float2 p0 = red[row][0], p1 = red[row][1], p2 = red[row][2], p3 = red[row][3];
                float s  = p0.x + p1.x + p2.x + p3.x;
                float sq = p0.y + p1.y + p2.y + p3.y;
                float mu  = s * (1.f / 256.f);
                float var = sq * (1.f / 256.f) - mu * mu;
                muv[mt][r] = mu;
                rsv[mt][r] = rsqrtf(var + 1e-5f);
            }

        #pragma unroll
        for (int mt = 0; mt < 2; ++mt)
            #pragma unroll
            for (int r = 0; r < 4; ++r) {
                float dot = 0.f;
                #pragma unroll
                for (int i = 0; i < 4; ++i) {
                    float o = fmaxf((acc2[mt][i][r] - muv[mt][r]) * rsv[mt][r] * gv[i] + bv[i], 0.f);
                    dot += o * lwv[i];
                }
                #pragma unroll
                for (int off = 1; off <= 8; off <<= 1)
                    dot += __shfl_xor(dot, off, 64);
                if (mrow == 0) red2[mt * 16 + q * 4 + r][wv] = dot;
            }
        __syncthreads();
        if (t < MT) {
            float d = red2[t][0] + red2[t][1] + red2[t][2] + red2[t][3];
            dup[b * Ln + l0 + t] = fmaxf(d + lb[0], 0.f);
        }
    }
}

extern "C" void kernel_launch(void* const* d_in, const int* in_sizes, int n_in,
                              void* d_out, int out_size, void* d_ws, size_t ws_size,
                              hipStream_t stream) {
    const float* x    = (const float*)d_in[0];
    const int*   targ = (const int*)d_in[1];
    // d_in[2] = mel_max_length (scalar) = 2048, hardcoded
    const float* c1w = (const float*)d_in[3];
    const float* c1b = (const float*)d_in[4];
    const float* g1  = (const float*)d_in[5];
    const float* be1 = (const float*)d_in[6];
    const float* c2w = (const float*)d_in[7];
    const float* c2b = (const float*)d_in[8];
    const float* g2  = (const float*)d_in[9];
    const float* be2 = (const float*)d_in[10];
    const float* lw  = (const float*)d_in[11];
    const float* lb  = (const float*)d_in[12];

    float* out     = (float*)d_out;                       // (B,M,C)
    float* out_dup = out + (size_t)Bn * Mn * Cn;          // (B,L)

    // workspace layout (no h1 round-trip)
    char* ws = (char*)d_ws;
    unsigned short* bp1 = (unsigned short*)ws;                       // 384 KiB
    unsigned short* bp2 = (unsigned short*)(ws + 393216);            // 384 KiB
    int*            map = (int*)(ws + 2 * 393216);                   // 128 KiB

    // K1: weight pack (192 blocks) + duration scan (16 blocks)
    pack_scan<<<208, 256, 0, stream>>>(c1w, c2w, bp1, bp2, targ, map);

    // K2: fused conv1+conv2+linear (blocks 0..255) + gather (blocks 256..2303)
    conv12_gather<<<NCONVBLK + NGATHERBLK, 256, 0, stream>>>(
        x, bp1, bp2, c1b, g1, be1, c2b, g2, be2, lw, lb,
        map, out, out_dup);
}

// Round 4
// 121.440 us; speedup vs baseline: 1.6745x; 1.0386x over previous
//
#include <hip/hip_runtime.h>
#include <hip/hip_bf16.h>

// Problem constants (fixed by reference):
//   B=16, L=512, D=C=F=256, K=3, M=2048, EPS=1e-5
#define Bn 16
#define Ln 512
#define Cn 256
#define Fn 256
#define Kn 3
#define Mn 2048

#define NKSTEP 24        // 768 / 32
#define MT 32            // output L-rows per conv block -> 256 conv blocks
#define XS_PS 264        // LDS slab row stride (bf16 units); 528 B = 33*16
#define XROWS 50         // staged x rows: global l0-9 .. l0+40
#define HROWS 48         // conv1 computed h rows: global l0-8 .. l0+39 (3 m-tiles)
#define HOFF  8          // h local row j <-> global l0 - HOFF + j
#define NCONVBLK 256
#define NGATHERBLK 1024  // 512 threads x 4 float4 = 2048 f4/block; 1024*2048 = B*M*C/4

typedef __attribute__((ext_vector_type(8))) short short8;
typedef __attribute__((ext_vector_type(4))) float f32x4;

static __device__ __forceinline__ unsigned short f2bf(float f) {
    unsigned int u = __float_as_uint(f);
    return (unsigned short)((u + 0x7fff + ((u >> 16) & 1)) >> 16);   // RNE
}

// ---------- K1: weight pack (vectorized short8 dest) + duration scan ----------
// blocks 0..15: per-batch cumsum of target -> m->l map (-1 = zero-fill).
// blocks 16..207: pack. bp[((s*16+nt)*64+lane)*8+j] = w[f=nt*16+(lane&15)][d][k],
//   kappa = k*256+d = s*32 + (lane>>4)*8 + j.  One contiguous short8 per thread.
__global__ __launch_bounds__(256) void pack_scan(
    const float* __restrict__ w1, const float* __restrict__ w2,
    unsigned short* __restrict__ bp1, unsigned short* __restrict__ bp2,
    const int* __restrict__ target, int* __restrict__ map)
{
    __shared__ int ss[256];
    const int blk = blockIdx.x;
    const int t = threadIdx.x;
    if (blk < 16) {
        const int bb = blk;
        int v0 = target[bb * Ln + 2 * t];
        int v1 = target[bb * Ln + 2 * t + 1];
        ss[t] = v0 + v1;
        __syncthreads();
        for (int off = 1; off < 256; off <<= 1) {
            int add = (t >= off) ? ss[t - off] : 0;
            __syncthreads();
            ss[t] += add;
            __syncthreads();
        }
        int S     = ss[t];        // inclusive pair-scan -> cumsum at 2t+1
        int total = ss[255];
        int cs1   = S;
        int cs0   = S - v1;
        int prev0 = cs0 - v0;
        for (int m = prev0; m < cs0; ++m) map[bb * Mn + m] = 2 * t;
        for (int m = cs0;   m < cs1; ++m) map[bb * Mn + m] = 2 * t + 1;
        for (int m = total + t; m < Mn; m += 256) map[bb * Mn + m] = -1;
    } else {
        // 192 blocks * 256 threads = 49152 short8 units (24576 per conv)
        int v = (blk - 16) * 256 + t;
        const float* w = w1;
        unsigned short* bp = bp1;
        if (v >= 24576) { v -= 24576; w = w2; bp = bp2; }
        int lane = v & 63, nt = (v >> 6) & 15, s = v >> 10;
        int f    = nt * 16 + (lane & 15);
        int kap0 = s * 32 + (lane >> 4) * 8;          // 8-aligned -> k fixed over j
        const float* p = w + ((size_t)f * Cn + (kap0 & 255)) * Kn + (kap0 >> 8);
        short8 o;
        #pragma unroll
        for (int j = 0; j < 8; ++j) o[j] = (short)f2bf(p[3 * j]);
        *(short8*)(bp + (size_t)v * 8) = o;
    }
}

// ---------- K2: fused conv1(48 rows, halo recompute) -> LDS -> conv2 + linear head,
//                plus length-regulate gather on independent blocks ----------
// Conv blocks (0..255): 512 threads = 8 waves; wave wv owns 32 output cols (2 n-tiles)
//   -> 2 waves/SIMD during the conv tail (latency hiding) and low reg pressure,
//   which lets us keep the 2-deep prefetch ring without spilling (round-2 lesson:
//   no min-waves launch bound; round-3 lesson: 1 wave/SIMD + no ring = latency-bound).
// A-frag (16x16x32): A[m=lane&15][k=(lane>>4)*8+j]; C/D: col=lane&15, row=(lane>>4)*4+reg.
// conv1 computes h rows l0-8..l0+39 (garbage outside [l0-1,l0+32] never read by conv2).
// h kept in LDS (aliases xs after conv1 reads complete) -> no global h round-trip.
__global__ __launch_bounds__(512) void conv12_gather(
    const float* __restrict__ x,                // (B,L,C) f32
    const unsigned short* __restrict__ bp1,     // packed conv1 weights
    const unsigned short* __restrict__ bp2,     // packed conv2 weights
    const float* __restrict__ c1b, const float* __restrict__ g1, const float* __restrict__ be1,
    const float* __restrict__ c2b, const float* __restrict__ g2, const float* __restrict__ be2,
    const float* __restrict__ lw,  const float* __restrict__ lb,
    const int* __restrict__ gmap,               // (B,M)
    float* __restrict__ out,                    // (B,M,C)
    float* __restrict__ dup)                    // (B,L)
{
    __shared__ __align__(16) unsigned short xs[XROWS * XS_PS];  // 26.4 KB; h aliases rows 0..47
    __shared__ float2 red[HROWS][8];                            // 3 KB
    __shared__ float  red2[MT][8];                              // 1 KB

    const int t = threadIdx.x;

    if (blockIdx.x >= NCONVBLK) {
        // ---- length-regulate gather: out[b,m,:] = (map>=0) ? x[b,map,:] : 0 ----
        // 4 independent float4 per thread: batch map loads, then x loads, then stores.
        const int base = (blockIdx.x - NCONVBLK) * 512 + t;   // 0 .. 524287
        int lv[4];
        #pragma unroll
        for (int i = 0; i < 4; ++i)
            lv[i] = gmap[(base + i * 524288) >> 6];
        float4 val[4];
        #pragma unroll
        for (int i = 0; i < 4; ++i) {
            int e4 = base + i * 524288;
            int d4 = e4 & 63;
            int b  = e4 >> 17;                 // bm>>11, bm=e4>>6
            val[i] = make_float4(0.f, 0.f, 0.f, 0.f);
            if (lv[i] >= 0)
                val[i] = *((const float4*)(x + (size_t)(b * Ln + lv[i]) * Cn) + d4);
        }
        #pragma unroll
        for (int i = 0; i < 4; ++i)
            ((float4*)out)[base + i * 524288] = val[i];
        return;
    }

    const int b  = blockIdx.x >> 4;          // 16 l-tiles per batch
    const int l0 = (blockIdx.x & 15) * MT;

    // ---- stage x rows l0-9 .. l0+40, zero-padded, as bf16 ----
    for (int idx = t; idx < XROWS * 64; idx += 512) {   // 64 float4 per row
        int row = idx >> 6;
        int c4  = (idx & 63) * 4;
        int l = l0 - 9 + row;
        float4 v = make_float4(0.f, 0.f, 0.f, 0.f);
        if (l >= 0 && l < Ln) v = *(const float4*)&x[((size_t)b * Ln + l) * Cn + c4];
        unsigned int lo = (unsigned int)f2bf(v.x) | ((unsigned int)f2bf(v.y) << 16);
        unsigned int hi = (unsigned int)f2bf(v.z) | ((unsigned int)f2bf(v.w) << 16);
        *(uint2*)&xs[row * XS_PS + c4] = make_uint2(lo, hi);
    }
    __syncthreads();

    const int lane = t & 63;
    const int wv   = t >> 6;      // wave 0..7: owns cols wv*32 .. wv*32+31 (n-tiles wv*2, wv*2+1)
    const int mrow = lane & 15;
    const int q    = lane >> 4;

    // ================= conv1: 3 m-tiles (h rows l0-8 .. l0+39) =================
    f32x4  acc1[3][2] = {};
    {
        short8 bfr[2][2];         // 2-slot ring, loaded 2 steps ahead
        short8 afr[2][3];

        auto loadB1 = [&](int s, int slot) {
            const unsigned short* p = bp1 + (size_t)((s * 16 + wv * 2) * 64 + lane) * 8;
            bfr[slot][0] = *(const short8*)p;
            bfr[slot][1] = *(const short8*)(p + 64 * 8);
        };
        auto loadA1 = [&](int s, int slot) {
            const int k    = s >> 3;
            const int dcol = (s & 7) * 32 + q * 8;
            #pragma unroll
            for (int mt = 0; mt < 3; ++mt)
                afr[slot][mt] = *(const short8*)&xs[(mt * 16 + mrow + k) * XS_PS + dcol];
        };

        loadB1(0, 0); loadA1(0, 0);
        loadB1(1, 1); loadA1(1, 1);

        #pragma unroll 2
        for (int s = 0; s < NKSTEP; ++s) {
            const int slot = s & 1;
            #pragma unroll
            for (int mt = 0; mt < 3; ++mt)
                #pragma unroll
                for (int i = 0; i < 2; ++i)
                    acc1[mt][i] = __builtin_amdgcn_mfma_f32_16x16x32_bf16(
                        afr[slot][mt], bfr[slot][i], acc1[mt][i], 0, 0, 0);
            const int sn = (s + 2 < NKSTEP) ? (s + 2) : s;   // tail: harmless reload
            loadB1(sn, slot);
            loadA1(sn, slot);
        }
    }

    // ---- epilogue 1: bias + LayerNorm stats (48 rows) ----
    {
        float gv[2], bv[2], biasv[2];
        #pragma unroll
        for (int i = 0; i < 2; ++i) {
            int col = wv * 32 + i * 16 + mrow;
            biasv[i] = c1b[col];
            gv[i]    = g1[col];
            bv[i]    = be1[col];
        }
        #pragma unroll
        for (int mt = 0; mt < 3; ++mt)
            #pragma unroll
            for (int i = 0; i < 2; ++i)
                #pragma unroll
                for (int r = 0; r < 4; ++r)
                    acc1[mt][i][r] += biasv[i];

        #pragma unroll
        for (int mt = 0; mt < 3; ++mt)
            #pragma unroll
            for (int r = 0; r < 4; ++r) {
                float s  = acc1[mt][0][r] + acc1[mt][1][r];
                float sq = acc1[mt][0][r] * acc1[mt][0][r] + acc1[mt][1][r] * acc1[mt][1][r];
                #pragma unroll
                for (int off = 1; off <= 8; off <<= 1) {
                    s  += __shfl_xor(s,  off, 64);
                    sq += __shfl_xor(sq, off, 64);
                }
                if (mrow == 0) red[mt * 16 + q * 4 + r][wv] = make_float2(s, sq);
            }
        __syncthreads();   // also guarantees all xs reads (conv1 A-frags) are done

        float muv[3][4], rsv[3][4];
        #pragma unroll
        for (int mt = 0; mt < 3; ++mt)
            #pragma unroll
            for (int r = 0; r < 4; ++r) {
                int row = mt * 16 + q * 4 + r;
                float s = 0.f, sq = 0.f;
                #pragma unroll
                for (int w = 0; w < 8; ++w) {
                    float2 pp = red[row][w];
                    s += pp.x; sq += pp.y;
                }
                float mu  = s * (1.f / 256.f);
                float var = sq * (1.f / 256.f) - mu * mu;
                muv[mt][r] = mu;
                rsv[mt][r] = rsqrtf(var + 1e-5f);
            }

        // ---- write h = relu(LN(conv1)) into LDS (aliases xs rows 0..47) ----
        // zero rows whose global l is out of [0,Ln) (conv2 SAME-pad boundary)
        #pragma unroll
        for (int mt = 0; mt < 3; ++mt)
            #pragma unroll
            for (int r = 0; r < 4; ++r) {
                int jr = mt * 16 + q * 4 + r;
                int l  = l0 - HOFF + jr;
                bool ok = (l >= 0 && l < Ln);
                #pragma unroll
                for (int i = 0; i < 2; ++i) {
                    float o = ok ? fmaxf((acc1[mt][i][r] - muv[mt][r]) * rsv[mt][r] * gv[i] + bv[i], 0.f)
                                 : 0.f;
                    xs[jr * XS_PS + (wv * 32 + i * 16 + mrow)] = f2bf(o);
                }
            }
    }
    __syncthreads();

    // ================= conv2: 2 m-tiles (output rows l0 .. l0+31) =================
    f32x4  acc2[2][2] = {};
    {
        short8 bfr[2][2];
        short8 afr[2][2];

        auto loadB2 = [&](int s, int slot) {
            const unsigned short* p = bp2 + (size_t)((s * 16 + wv * 2) * 64 + lane) * 8;
            bfr[slot][0] = *(const short8*)p;
            bfr[slot][1] = *(const short8*)(p + 64 * 8);
        };
        // output row j reads h global l0+j-1+k <-> h local row j+k+HOFF-1 = j+k+7
        auto loadA2 = [&](int s, int slot) {
            const int k    = s >> 3;
            const int dcol = (s & 7) * 32 + q * 8;
            #pragma unroll
            for (int mt = 0; mt < 2; ++mt)
                afr[slot][mt] = *(const short8*)&xs[(mt * 16 + mrow + k + 7) * XS_PS + dcol];
        };

        loadB2(0, 0); loadA2(0, 0);
        loadB2(1, 1); loadA2(1, 1);

        #pragma unroll 2
        for (int s = 0; s < NKSTEP; ++s) {
            const int slot = s & 1;
            #pragma unroll
            for (int mt = 0; mt < 2; ++mt)
                #pragma unroll
                for (int i = 0; i < 2; ++i)
                    acc2[mt][i] = __builtin_amdgcn_mfma_f32_16x16x32_bf16(
                        afr[slot][mt], bfr[slot][i], acc2[mt][i], 0, 0, 0);
            const int sn = (s + 2 < NKSTEP) ? (s + 2) : s;
            loadB2(sn, slot);
            loadA2(sn, slot);
        }
    }

    // ---- epilogue 2: bias + LN + ReLU + linear head -> dup ----
    {
        float gv[2], bv[2], biasv[2], lwv[2];
        #pragma unroll
        for (int i = 0; i < 2; ++i) {
            int col = wv * 32 + i * 16 + mrow;
            biasv[i] = c2b[col];
            gv[i]    = g2[col];
            bv[i]    = be2[col];
            lwv[i]   = lw[col];
        }
        #pragma unroll
        for (int mt = 0; mt < 2; ++mt)
            #pragma unroll
            for (int i = 0; i < 2; ++i)
                #pragma unroll
                for (int r = 0; r < 4; ++r)
                    acc2[mt][i][r] += biasv[i];

        #pragma unroll
        for (int mt = 0; mt < 2; ++mt)
            #pragma unroll
            for (int r = 0; r < 4; ++r) {
                float s  = acc2[mt][0][r] + acc2[mt][1][r];
                float sq = acc2[mt][0][r] * acc2[mt][0][r] + acc2[mt][1][r] * acc2[mt][1][r];
                #pragma unroll
                for (int off = 1; off <= 8; off <<= 1) {
                    s  += __shfl_xor(s,  off, 64);
                    sq += __shfl_xor(sq, off, 64);
                }
                if (mrow == 0) red[mt * 16 + q * 4 + r][wv] = make_float2(s, sq);
            }
        __syncthreads();

        float muv[2][4], rsv[2][4];
        #pragma unroll
        for (int mt = 0; mt < 2; ++mt)
            #pragma unroll
            for (int r = 0; r < 4; ++r) {
                int row = mt * 16 + q * 4 + r;
                float s = 0.f, sq = 0.f;
                #pragma unroll
                for (int w = 0; w < 8; ++w) {
                    float2 pp = red[row][w];
                    s += pp.x; sq += pp.y;
                }
                float mu  = s * (1.f / 256.f);
                float var = sq * (1.f / 256.f) - mu * mu;
                muv[mt][r] = mu;
                rsv[mt][r] = rsqrtf(var + 1e-5f);
            }

        #pragma unroll
        for (int mt = 0; mt < 2; ++mt)
            #pragma unroll
            for (int r = 0; r < 4; ++r) {
                float dot = 0.f;
                #pragma unroll
                for (int i = 0; i < 2; ++i) {
                    float o = fmaxf((acc2[mt][i][r] - muv[mt][r]) * rsv[mt][r] * gv[i] + bv[i], 0.f);
                    dot += o * lwv[i];
                }
                #pragma unroll
                for (int off = 1; off <= 8; off <<= 1)
                    dot += __shfl_xor(dot, off, 64);
                if (mrow == 0) red2[mt * 16 + q * 4 + r][wv] = dot;
            }
        __syncthreads();
        if (t < MT) {
            float d = red2[t][0] + red2[t][1] + red2[t][2] + red2[t][3]
                    + red2[t][4] + red2[t][5] + red2[t][6] + red2[t][7];
            dup[b * Ln + l0 + t] = fmaxf(d + lb[0], 0.f);
        }
    }
}

extern "C" void kernel_launch(void* const* d_in, const int* in_sizes, int n_in,
                              void* d_out, int out_size, void* d_ws, size_t ws_size,
                              hipStream_t stream) {
    const float* x    = (const float*)d_in[0];
    const int*   targ = (const int*)d_in[1];
    // d_in[2] = mel_max_length (scalar) = 2048, hardcoded
    const float* c1w = (const float*)d_in[3];
    const float* c1b = (const float*)d_in[4];
    const float* g1  = (const float*)d_in[5];
    const float* be1 = (const float*)d_in[6];
    const float* c2w = (const float*)d_in[7];
    const float* c2b = (const float*)d_in[8];
    const float* g2  = (const float*)d_in[9];
    const float* be2 = (const float*)d_in[10];
    const float* lw  = (const float*)d_in[11];
    const float* lb  = (const float*)d_in[12];

    float* out     = (float*)d_out;                       // (B,M,C)
    float* out_dup = out + (size_t)Bn * Mn * Cn;          // (B,L)

    // workspace layout (no h1 round-trip)
    char* ws = (char*)d_ws;
    unsigned short* bp1 = (unsigned short*)ws;                       // 384 KiB
    unsigned short* bp2 = (unsigned short*)(ws + 393216);            // 384 KiB
    int*            map = (int*)(ws + 2 * 393216);                   // 128 KiB

    // K1: weight pack (192 blocks) + duration scan (16 blocks)
    pack_scan<<<208, 256, 0, stream>>>(c1w, c2w, bp1, bp2, targ, map);

    // K2: fused conv1+conv2+linear (blocks 0..255, 8 waves each)
    //     + gather (blocks 256..1279, 512 threads x 4 float4)
    conv12_gather<<<NCONVBLK + NGATHERBLK, 512, 0, stream>>>(
        x, bp1, bp2, c1b, g1, be1, c2b, g2, be2, lw, lb,
        map, out, out_dup);
}

// Round 6
// 119.517 us; speedup vs baseline: 1.7014x; 1.0161x over previous
//
#include <hip/hip_runtime.h>
#include <hip/hip_bf16.h>

// Problem constants (fixed by reference):
//   B=16, L=512, D=C=F=256, K=3, M=2048, EPS=1e-5
#define Bn 16
#define Ln 512
#define Cn 256
#define Fn 256
#define Kn 3
#define Mn 2048

#define NKSTEP 24        // 768 / 32
#define MT 32            // output L-rows per conv block -> 256 conv blocks
#define XS_PS 264        // LDS slab row stride (bf16 units); 528 B = 33*16
#define XROWS 50         // staged x rows: global l0-9 .. l0+40
#define HROWS 48         // conv1 computed h rows: global l0-8 .. l0+39 (3 m-tiles)
#define HOFF  8          // h local row j <-> global l0 - HOFF + j
#define NCONVBLK 256
#define NGATHERBLK 2048  // 256 threads x 4 float4; 2048*1024 = B*M*C/4

typedef __attribute__((ext_vector_type(8))) short short8;
typedef __attribute__((ext_vector_type(4))) float f32x4;

static __device__ __forceinline__ unsigned short f2bf(float f) {
    unsigned int u = __float_as_uint(f);
    return (unsigned short)((u + 0x7fff + ((u >> 16) & 1)) >> 16);   // RNE
}

// ---------- K1: weight pack (vectorized short8 dest) + duration scan ----------
// blocks 0..15: per-batch cumsum of target -> m->l map (-1 = zero-fill).
// blocks 16..207: pack. bp[((s*16+nt)*64+lane)*8+j] = w[f=nt*16+(lane&15)][d][k],
//   kappa = k*256+d = s*32 + (lane>>4)*8 + j.  One contiguous short8 per thread.
// (bit-identical to rounds 2-4, all passed)
__global__ __launch_bounds__(256) void pack_scan(
    const float* __restrict__ w1, const float* __restrict__ w2,
    unsigned short* __restrict__ bp1, unsigned short* __restrict__ bp2,
    const int* __restrict__ target, int* __restrict__ map)
{
    __shared__ int ss[256];
    const int blk = blockIdx.x;
    const int t = threadIdx.x;
    if (blk < 16) {
        const int bb = blk;
        int v0 = target[bb * Ln + 2 * t];
        int v1 = target[bb * Ln + 2 * t + 1];
        ss[t] = v0 + v1;
        __syncthreads();
        for (int off = 1; off < 256; off <<= 1) {
            int add = (t >= off) ? ss[t - off] : 0;
            __syncthreads();
            ss[t] += add;
            __syncthreads();
        }
        int S     = ss[t];        // inclusive pair-scan -> cumsum at 2t+1
        int total = ss[255];
        int cs1   = S;
        int cs0   = S - v1;
        int prev0 = cs0 - v0;
        for (int m = prev0; m < cs0; ++m) map[bb * Mn + m] = 2 * t;
        for (int m = cs0;   m < cs1; ++m) map[bb * Mn + m] = 2 * t + 1;
        for (int m = total + t; m < Mn; m += 256) map[bb * Mn + m] = -1;
    } else {
        // 192 blocks * 256 threads = 49152 short8 units (24576 per conv)
        int v = (blk - 16) * 256 + t;
        const float* w = w1;
        unsigned short* bp = bp1;
        if (v >= 24576) { v -= 24576; w = w2; bp = bp2; }
        int lane = v & 63, nt = (v >> 6) & 15, s = v >> 10;
        int f    = nt * 16 + (lane & 15);
        int kap0 = s * 32 + (lane >> 4) * 8;          // 8-aligned -> k fixed over j
        const float* p = w + ((size_t)f * Cn + (kap0 & 255)) * Kn + (kap0 >> 8);
        short8 o;
        #pragma unroll
        for (int j = 0; j < 8; ++j) o[j] = (short)f2bf(p[3 * j]);
        *(short8*)(bp + (size_t)v * 8) = o;
    }
}

// ---------- K2: fused conv1(48 rows, halo recompute) -> LDS -> conv2 + linear head,
//                plus length-regulate gather on independent blocks ----------
// Conv blocks (0..255): 256 threads = 4 waves; wave owns 64 cols (4 n-tiles) —
//   best LDS A-frag reuse (r4 lesson: Nw=32 doubled LDS reads).
// Inner loop is the round-0/round-2 proven pattern: full 2-deep A+B rings with
//   UNCONDITIONAL harmless-reload tail (r5's conditional-tail variant failed the
//   post-timing check; every passing round used this exact pattern).
// No min-waves launch bound (r2 lesson: (256,4) forced 128-reg budget -> 14.6 MB spill).
// A-frag (16x16x32): A[m=lane&15][k=(lane>>4)*8+j]; C/D: col=lane&15, row=(lane>>4)*4+reg.
// conv1 computes h rows l0-8..l0+39 (garbage outside [l0-1,l0+32] never read by conv2).
// h kept in LDS (aliases xs after conv1 reads complete) -> no global h round-trip.
__global__ __launch_bounds__(256) void conv12_gather(
    const float* __restrict__ x,                // (B,L,C) f32
    const unsigned short* __restrict__ bp1,     // packed conv1 weights
    const unsigned short* __restrict__ bp2,     // packed conv2 weights
    const float* __restrict__ c1b, const float* __restrict__ g1, const float* __restrict__ be1,
    const float* __restrict__ c2b, const float* __restrict__ g2, const float* __restrict__ be2,
    const float* __restrict__ lw,  const float* __restrict__ lb,
    const int* __restrict__ gmap,               // (B,M)
    float* __restrict__ out,                    // (B,M,C)
    float* __restrict__ dup)                    // (B,L)
{
    __shared__ __align__(16) unsigned short xs[XROWS * XS_PS];  // 26.4 KB; h aliases rows 0..47
    __shared__ float2 red[HROWS][4];                            // 1.5 KB
    __shared__ float  red2[MT][4];                              // 0.5 KB

    const int t = threadIdx.x;

    if (blockIdx.x >= NCONVBLK) {
        // ---- length-regulate gather: out[b,m,:] = (map>=0) ? x[b,map,:] : 0 ----
        // (bit-identical to round 3 / round 4, both passed)
        const int base = (blockIdx.x - NCONVBLK) * 256 + t;   // 0 .. 524287
        int lv[4];
        #pragma unroll
        for (int i = 0; i < 4; ++i)
            lv[i] = gmap[(base + i * 524288) >> 6];
        float4 val[4];
        #pragma unroll
        for (int i = 0; i < 4; ++i) {
            int e4 = base + i * 524288;
            int d4 = e4 & 63;
            int b  = e4 >> 17;                 // bm>>11, bm=e4>>6
            val[i] = make_float4(0.f, 0.f, 0.f, 0.f);
            if (lv[i] >= 0)
                val[i] = *((const float4*)(x + (size_t)(b * Ln + lv[i]) * Cn) + d4);
        }
        #pragma unroll
        for (int i = 0; i < 4; ++i)
            ((float4*)out)[base + i * 524288] = val[i];
        return;
    }

    const int b  = blockIdx.x >> 4;          // 16 l-tiles per batch
    const int l0 = (blockIdx.x & 15) * MT;

    // ---- stage x rows l0-9 .. l0+40, zero-padded, as bf16 ----
    for (int idx = t; idx < XROWS * 64; idx += 256) {   // 64 float4 per row
        int row = idx >> 6;
        int c4  = (idx & 63) * 4;
        int l = l0 - 9 + row;
        float4 v = make_float4(0.f, 0.f, 0.f, 0.f);
        if (l >= 0 && l < Ln) v = *(const float4*)&x[((size_t)b * Ln + l) * Cn + c4];
        unsigned int lo = (unsigned int)f2bf(v.x) | ((unsigned int)f2bf(v.y) << 16);
        unsigned int hi = (unsigned int)f2bf(v.z) | ((unsigned int)f2bf(v.w) << 16);
        *(uint2*)&xs[row * XS_PS + c4] = make_uint2(lo, hi);
    }
    __syncthreads();

    const int lane = t & 63;
    const int wv   = t >> 6;      // n-group: cols wv*64 .. wv*64+63
    const int mrow = lane & 15;
    const int q    = lane >> 4;

    // ================= conv1: 3 m-tiles (h rows l0-8 .. l0+39) =================
    f32x4  acc1[3][4] = {};
    {
        short8 bfr[2][4];         // 2-slot ring, loaded 2 steps ahead (proven r0/r2 pattern)
        short8 afr[2][3];

        auto loadB1 = [&](int s, int slot) {
            const unsigned short* p = bp1 + (size_t)((s * 16 + wv * 4) * 64 + lane) * 8;
            #pragma unroll
            for (int i = 0; i < 4; ++i)
                bfr[slot][i] = *(const short8*)(p + (size_t)i * 64 * 8);
        };
        auto loadA1 = [&](int s, int slot) {
            const int k    = s >> 3;
            const int dcol = (s & 7) * 32 + q * 8;
            #pragma unroll
            for (int mt = 0; mt < 3; ++mt)
                afr[slot][mt] = *(const short8*)&xs[(mt * 16 + mrow + k) * XS_PS + dcol];
        };

        loadB1(0, 0); loadA1(0, 0);
        loadB1(1, 1); loadA1(1, 1);

        #pragma unroll 2
        for (int s = 0; s < NKSTEP; ++s) {
            const int slot = s & 1;
            #pragma unroll
            for (int mt = 0; mt < 3; ++mt)
                #pragma unroll
                for (int i = 0; i < 4; ++i)
                    acc1[mt][i] = __builtin_amdgcn_mfma_f32_16x16x32_bf16(
                        afr[slot][mt], bfr[slot][i], acc1[mt][i], 0, 0, 0);
            const int sn = (s + 2 < NKSTEP) ? (s + 2) : s;   // tail: harmless reload
            loadB1(sn, slot);
            loadA1(sn, slot);
        }
    }

    // ---- epilogue 1: bias + LayerNorm stats (48 rows) ----
    {
        float gv[4], bv[4], biasv[4];
        #pragma unroll
        for (int i = 0; i < 4; ++i) {
            int col = wv * 64 + i * 16 + mrow;
            biasv[i] = c1b[col];
            gv[i]    = g1[col];
            bv[i]    = be1[col];
        }
        #pragma unroll
        for (int mt = 0; mt < 3; ++mt)
            #pragma unroll
            for (int i = 0; i < 4; ++i)
                #pragma unroll
                for (int r = 0; r < 4; ++r)
                    acc1[mt][i][r] += biasv[i];

        #pragma unroll
        for (int mt = 0; mt < 3; ++mt)
            #pragma unroll
            for (int r = 0; r < 4; ++r) {
                float s  = acc1[mt][0][r] + acc1[mt][1][r] + acc1[mt][2][r] + acc1[mt][3][r];
                float sq = acc1[mt][0][r] * acc1[mt][0][r] + acc1[mt][1][r] * acc1[mt][1][r]
                         + acc1[mt][2][r] * acc1[mt][2][r] + acc1[mt][3][r] * acc1[mt][3][r];
                #pragma unroll
                for (int off = 1; off <= 8; off <<= 1) {
                    s  += __shfl_xor(s,  off, 64);
                    sq += __shfl_xor(sq, off, 64);
                }
                if (mrow == 0) red[mt * 16 + q * 4 + r][wv] = make_float2(s, sq);
            }
        __syncthreads();   // also guarantees all xs reads (conv1 A-frags) are done

        float muv[3][4], rsv[3][4];
        #pragma unroll
        for (int mt = 0; mt < 3; ++mt)
            #pragma unroll
            for (int r = 0; r < 4; ++r) {
                int row = mt * 16 + q * 4 + r;
                float2 p0 = red[row][0], p1 = red[row][1], p2 = red[row][2], p3 = red[row][3];
                float s  = p0.x + p1.x + p2.x + p3.x;
                float sq = p0.y + p1.y + p2.y + p3.y;
                float mu  = s * (1.f / 256.f);
                float var = sq * (1.f / 256.f) - mu * mu;
                muv[mt][r] = mu;
                rsv[mt][r] = rsqrtf(var + 1e-5f);
            }

        // ---- write h = relu(LN(conv1)) into LDS (aliases xs rows 0..47) ----
        // zero rows whose global l is out of [0,Ln) (conv2 SAME-pad boundary)
        #pragma unroll
        for (int mt = 0; mt < 3; ++mt)
            #pragma unroll
            for (int r = 0; r < 4; ++r) {
                int jr = mt * 16 + q * 4 + r;
                int l  = l0 - HOFF + jr;
                bool ok = (l >= 0 && l < Ln);
                #pragma unroll
                for (int i = 0; i < 4; ++i) {
                    float o = ok ? fmaxf((acc1[mt][i][r] - muv[mt][r]) * rsv[mt][r] * gv[i] + bv[i], 0.f)
                                 : 0.f;
                    xs[jr * XS_PS + (wv * 64 + i * 16 + mrow)] = f2bf(o);
                }
            }
    }
    __syncthreads();

    // ================= conv2: 2 m-tiles (output rows l0 .. l0+31) =================
    f32x4  acc2[2][4] = {};
    {
        short8 bfr[2][4];
        short8 afr[2][2];

        auto loadB2 = [&](int s, int slot) {
            const unsigned short* p = bp2 + (size_t)((s * 16 + wv * 4) * 64 + lane) * 8;
            #pragma unroll
            for (int i = 0; i < 4; ++i)
                bfr[slot][i] = *(const short8*)(p + (size_t)i * 64 * 8);
        };
        // output row j reads h global l0+j-1+k <-> h local row j+k+HOFF-1 = j+k+7
        auto loadA2 = [&](int s, int slot) {
            const int k    = s >> 3;
            const int dcol = (s & 7) * 32 + q * 8;
            #pragma unroll
            for (int mt = 0; mt < 2; ++mt)
                afr[slot][mt] = *(const short8*)&xs[(mt * 16 + mrow + k + 7) * XS_PS + dcol];
        };

        loadB2(0, 0); loadA2(0, 0);
        loadB2(1, 1); loadA2(1, 1);

        #pragma unroll 2
        for (int s = 0; s < NKSTEP; ++s) {
            const int slot = s & 1;
            #pragma unroll
            for (int mt = 0; mt < 2; ++mt)
                #pragma unroll
                for (int i = 0; i < 4; ++i)
                    acc2[mt][i] = __builtin_amdgcn_mfma_f32_16x16x32_bf16(
                        afr[slot][mt], bfr[slot][i], acc2[mt][i], 0, 0, 0);
            const int sn = (s + 2 < NKSTEP) ? (s + 2) : s;   // tail: harmless reload
            loadB2(sn, slot);
            loadA2(sn, slot);
        }
    }

    // ---- epilogue 2: bias + LN + ReLU + linear head -> dup ----
    {
        float gv[4], bv[4], biasv[4], lwv[4];
        #pragma unroll
        for (int i = 0; i < 4; ++i) {
            int col = wv * 64 + i * 16 + mrow;
            biasv[i] = c2b[col];
            gv[i]    = g2[col];
            bv[i]    = be2[col];
            lwv[i]   = lw[col];
        }
        #pragma unroll
        for (int mt = 0; mt < 2; ++mt)
            #pragma unroll
            for (int i = 0; i < 4; ++i)
                #pragma unroll
                for (int r = 0; r < 4; ++r)
                    acc2[mt][i][r] += biasv[i];

        #pragma unroll
        for (int mt = 0; mt < 2; ++mt)
            #pragma unroll
            for (int r = 0; r < 4; ++r) {
                float s  = acc2[mt][0][r] + acc2[mt][1][r] + acc2[mt][2][r] + acc2[mt][3][r];
                float sq = acc2[mt][0][r] * acc2[mt][0][r] + acc2[mt][1][r] * acc2[mt][1][r]
                         + acc2[mt][2][r] * acc2[mt][2][r] + acc2[mt][3][r] * acc2[mt][3][r];
                #pragma unroll
                for (int off = 1; off <= 8; off <<= 1) {
                    s  += __shfl_xor(s,  off, 64);
                    sq += __shfl_xor(sq, off, 64);
                }
                if (mrow == 0) red[mt * 16 + q * 4 + r][wv] = make_float2(s, sq);
            }
        __syncthreads();

        float muv[2][4], rsv[2][4];
        #pragma unroll
        for (int mt = 0; mt < 2; ++mt)
            #pragma unroll
            for (int r = 0; r < 4; ++r) {
                int row = mt * 16 + q * 4 + r;
                float2 p0 = red[row][0], p1 = red[row][1], p2 = red[row][2], p3 = red[row][3];
                float s  = p0.x + p1.x + p2.x + p3.x;
                float sq = p0.y + p1.y + p2.y + p3.y;
                float mu  = s * (1.f / 256.f);
                float var = sq * (1.f / 256.f) - mu * mu;
                muv[mt][r] = mu;
                rsv[mt][r] = rsqrtf(var + 1e-5f);
            }

        #pragma unroll
        for (int mt = 0; mt < 2; ++mt)
            #pragma unroll
            for (int r = 0; r < 4; ++r) {
                float dot = 0.f;
                #pragma unroll
                for (int i = 0; i < 4; ++i) {
                    float o = fmaxf((acc2[mt][i][r] - muv[mt][r]) * rsv[mt][r] * gv[i] + bv[i], 0.f);
                    dot += o * lwv[i];
                }
                #pragma unroll
                for (int off = 1; off <= 8; off <<= 1)
                    dot += __shfl_xor(dot, off, 64);
                if (mrow == 0) red2[mt * 16 + q * 4 + r][wv] = dot;
            }
        __syncthreads();
        if (t < MT) {
            float d = red2[t][0] + red2[t][1] + red2[t][2] + red2[t][3];
            dup[b * Ln + l0 + t] = fmaxf(d + lb[0], 0.f);
        }
    }
}

extern "C" void kernel_launch(void* const* d_in, const int* in_sizes, int n_in,
                              void* d_out, int out_size, void* d_ws, size_t ws_size,
                              hipStream_t stream) {
    const float* x    = (const float*)d_in[0];
    const int*   targ = (const int*)d_in[1];
    // d_in[2] = mel_max_length (scalar) = 2048, hardcoded
    const float* c1w = (const float*)d_in[3];
    const float* c1b = (const float*)d_in[4];
    const float* g1  = (const float*)d_in[5];
    const float* be1 = (const float*)d_in[6];
    const float* c2w = (const float*)d_in[7];
    const float* c2b = (const float*)d_in[8];
    const float* g2  = (const float*)d_in[9];
    const float* be2 = (const float*)d_in[10];
    const float* lw  = (const float*)d_in[11];
    const float* lb  = (const float*)d_in[12];

    float* out     = (float*)d_out;                       // (B,M,C)
    float* out_dup = out + (size_t)Bn * Mn * Cn;          // (B,L)

    // workspace layout (no h1 round-trip)
    char* ws = (char*)d_ws;
    unsigned short* bp1 = (unsigned short*)ws;                       // 384 KiB
    unsigned short* bp2 = (unsigned short*)(ws + 393216);            // 384 KiB
    int*            map = (int*)(ws + 2 * 393216);                   // 128 KiB

    // K1: weight pack (192 blocks) + duration scan (16 blocks)
    pack_scan<<<208, 256, 0, stream>>>(c1w, c2w, bp1, bp2, targ, map);

    // K2: fused conv1+conv2+linear (blocks 0..255, 4 waves each)
    //     + gather (blocks 256..2303, 256 threads x 4 float4)
    conv12_gather<<<NCONVBLK + NGATHERBLK, 256, 0, stream>>>(
        x, bp1, bp2, c1b, g1, be1, c2b, g2, be2, lw, lb,
        map, out, out_dup);
}

// Round 7
// 116.834 us; speedup vs baseline: 1.7405x; 1.0230x over previous
//
#include <hip/hip_runtime.h>
#include <hip/hip_bf16.h>

// Problem constants (fixed by reference):
//   B=16, L=512, D=C=F=256, K=3, M=2048, EPS=1e-5
#define Bn 16
#define Ln 512
#define Cn 256
#define Fn 256
#define Kn 3
#define Mn 2048

#define NKSTEP 24        // 768 / 32
#define MT 32            // L-rows per conv block -> 256 conv blocks
#define XS_PS 264        // LDS A-slab row stride (bf16 units); 528 B = 33*16
#define NCONVBLK 256
#define NGHALF 1024      // gather blocks per conv kernel (half of the gather each)
// each gather block: 256 thr x 4 float4, stride 262144; 2 x 1024 x 1024 f4 = B*M*C/4

typedef __attribute__((ext_vector_type(8))) short short8;
typedef __attribute__((ext_vector_type(4))) float f32x4;

static __device__ __forceinline__ unsigned short f2bf(float f) {
    unsigned int u = __float_as_uint(f);
    return (unsigned short)((u + 0x7fff + ((u >> 16) & 1)) >> 16);   // RNE
}

// ---------- K1: weight pack (vectorized short8 dest) + duration scan ----------
// blocks 0..15: per-batch cumsum of target -> m->l map (-1 = zero-fill).
// blocks 16..207: pack. bp[((s*16+nt)*64+lane)*8+j] = w[f=nt*16+(lane&15)][d][k],
//   kappa = k*256+d = s*32 + (lane>>4)*8 + j.  One contiguous short8 per thread.
// (bit-identical to rounds 2-4 and 6, all passed)
__global__ __launch_bounds__(256) void pack_scan(
    const float* __restrict__ w1, const float* __restrict__ w2,
    unsigned short* __restrict__ bp1, unsigned short* __restrict__ bp2,
    const int* __restrict__ target, int* __restrict__ map)
{
    __shared__ int ss[256];
    const int blk = blockIdx.x;
    const int t = threadIdx.x;
    if (blk < 16) {
        const int bb = blk;
        int v0 = target[bb * Ln + 2 * t];
        int v1 = target[bb * Ln + 2 * t + 1];
        ss[t] = v0 + v1;
        __syncthreads();
        for (int off = 1; off < 256; off <<= 1) {
            int add = (t >= off) ? ss[t - off] : 0;
            __syncthreads();
            ss[t] += add;
            __syncthreads();
        }
        int S     = ss[t];        // inclusive pair-scan -> cumsum at 2t+1
        int total = ss[255];
        int cs1   = S;
        int cs0   = S - v1;
        int prev0 = cs0 - v0;
        for (int m = prev0; m < cs0; ++m) map[bb * Mn + m] = 2 * t;
        for (int m = cs0;   m < cs1; ++m) map[bb * Mn + m] = 2 * t + 1;
        for (int m = total + t; m < Mn; m += 256) map[bb * Mn + m] = -1;
    } else {
        // 192 blocks * 256 threads = 49152 short8 units (24576 per conv)
        int v = (blk - 16) * 256 + t;
        const float* w = w1;
        unsigned short* bp = bp1;
        if (v >= 24576) { v -= 24576; w = w2; bp = bp2; }
        int lane = v & 63, nt = (v >> 6) & 15, s = v >> 10;
        int f    = nt * 16 + (lane & 15);
        int kap0 = s * 32 + (lane >> 4) * 8;          // 8-aligned -> k fixed over j
        const float* p = w + ((size_t)f * Cn + (kap0 & 255)) * Kn + (kap0 >> 8);
        short8 o;
        #pragma unroll
        for (int j = 0; j < 8; ++j) o[j] = (short)f2bf(p[3 * j]);
        *(short8*)(bp + (size_t)v * 8) = o;
    }
}

// ---------- fused conv1d(K=3,SAME) via MFMA + bias + LayerNorm + ReLU ----------
// Round-0 structure (best measured): conv blocks 0..255 = 32 L-rows of one batch,
// 4 waves, wave = 2 m-tiles x 4 n-tiles; h1 round-trips through global (L2-hot).
// NEW vs r0: the length-regulate gather is split in half across BOTH conv kernels
// (E4OFF template), so conv2's kernel also has streaming blocks co-resident to
// hide its latency (r0's K3 ran 256 lonely blocks); gather uses the r4/r6-proven
// 4-float4 batched-ILP form.
// A-frag (16x16x32): A[m=lane&15][k=(lane>>4)*8+j]; C/D: col=lane&15, row=(lane>>4)*4+reg.
template <bool IS_F32_IN, bool DO_LINEAR, int E4OFF>
__global__ __launch_bounds__(256) void conv_mfma(
    const void* __restrict__ in_,               // (B,L,C) f32 or bf16
    const unsigned short* __restrict__ bp,      // packed weights (bf16 frag order)
    const float* __restrict__ bias,             // (F)
    const float* __restrict__ gamma,            // (F)
    const float* __restrict__ beta,             // (F)
    const float* __restrict__ lw,               // (F)  [DO_LINEAR]
    const float* __restrict__ lb,               // (1)  [DO_LINEAR]
    unsigned short* __restrict__ hout,          // bf16 (B,L,F) [!DO_LINEAR]
    float* __restrict__ dup,                    // (B,L)        [DO_LINEAR]
    const float* __restrict__ gx,               // (B,L,C) f32  [gather]
    const int* __restrict__ gmap,               // (B,M)        [gather]
    float* __restrict__ gout)                   // (B,M,C)      [gather]
{
    __shared__ __align__(16) unsigned short xs[(MT + 2) * XS_PS];  // ~18 KB
    __shared__ float2 red[MT][4];                                  // 1 KB
    __shared__ float  red2[MT][4];                                 // 0.5 KB

    const int t = threadIdx.x;

    if (blockIdx.x >= NCONVBLK) {
        // ---- length-regulate gather half: out[b,m,:] = (map>=0) ? x[b,map,:] : 0 ----
        // 4 independent float4 per thread (proven r4/r6): batch map loads, then
        // x loads, then stores (memory-level parallelism).
        const int base = (blockIdx.x - NCONVBLK) * 256 + t;   // 0 .. 262143
        int lv[4];
        #pragma unroll
        for (int i = 0; i < 4; ++i)
            lv[i] = gmap[(E4OFF + base + i * 262144) >> 6];
        float4 val[4];
        #pragma unroll
        for (int i = 0; i < 4; ++i) {
            int e4 = E4OFF + base + i * 262144;
            int d4 = e4 & 63;
            int b  = e4 >> 17;                 // bm>>11, bm=e4>>6
            val[i] = make_float4(0.f, 0.f, 0.f, 0.f);
            if (lv[i] >= 0)
                val[i] = *((const float4*)(gx + (size_t)(b * Ln + lv[i]) * Cn) + d4);
        }
        #pragma unroll
        for (int i = 0; i < 4; ++i)
            ((float4*)gout)[E4OFF + base + i * 262144] = val[i];
        return;
    }

    const int b  = blockIdx.x >> 4;          // 16 l-tiles per batch
    const int l0 = (blockIdx.x & 15) * MT;

    // ---- stage input rows [l0-1, l0+32], zero-padded, as bf16 ----
    if (IS_F32_IN) {
        const float* in = (const float*)in_;
        for (int idx = t; idx < (MT + 2) * 64; idx += 256) {   // 64 float4 per row
            int row = idx >> 6;
            int c4  = (idx & 63) * 4;
            int l = l0 + row - 1;
            float4 v = make_float4(0.f, 0.f, 0.f, 0.f);
            if (l >= 0 && l < Ln) v = *(const float4*)&in[((size_t)b * Ln + l) * Cn + c4];
            unsigned int lo = (unsigned int)f2bf(v.x) | ((unsigned int)f2bf(v.y) << 16);
            unsigned int hi = (unsigned int)f2bf(v.z) | ((unsigned int)f2bf(v.w) << 16);
            *(uint2*)&xs[row * XS_PS + c4] = make_uint2(lo, hi);
        }
    } else {
        const unsigned short* in = (const unsigned short*)in_;
        for (int idx = t; idx < (MT + 2) * 32; idx += 256) {   // 32 x (8 bf16) per row
            int row = idx >> 5;
            int c8  = (idx & 31) * 8;
            int l = l0 + row - 1;
            uint4 v = make_uint4(0u, 0u, 0u, 0u);
            if (l >= 0 && l < Ln) v = *(const uint4*)&in[((size_t)b * Ln + l) * Cn + c8];
            *(uint4*)&xs[row * XS_PS + c8] = v;
        }
    }
    __syncthreads();

    const int lane = t & 63;
    const int wv   = t >> 6;      // n-group: cols wv*64 .. wv*64+63
    const int mrow = lane & 15;
    const int q    = lane >> 4;

    f32x4  acc[2][4] = {};
    short8 bfr[2][4];             // 2-slot ring, loaded 2 steps ahead
    short8 afr[2][2];

    auto loadB = [&](int s, int slot) {
        const unsigned short* p = bp + (size_t)((s * 16 + wv * 4) * 64 + lane) * 8;
        #pragma unroll
        for (int i = 0; i < 4; ++i)
            bfr[slot][i] = *(const short8*)(p + (size_t)i * 64 * 8);
    };
    auto loadA = [&](int s, int slot) {
        const int k    = s >> 3;
        const int dcol = (s & 7) * 32 + q * 8;
        #pragma unroll
        for (int mt = 0; mt < 2; ++mt)
            afr[slot][mt] = *(const short8*)&xs[(mt * 16 + mrow + k) * XS_PS + dcol];
    };

    loadB(0, 0); loadA(0, 0);
    loadB(1, 1); loadA(1, 1);

    #pragma unroll 2
    for (int s = 0; s < NKSTEP; ++s) {
        const int slot = s & 1;
        #pragma unroll
        for (int mt = 0; mt < 2; ++mt)
            #pragma unroll
            for (int i = 0; i < 4; ++i)
                acc[mt][i] = __builtin_amdgcn_mfma_f32_16x16x32_bf16(
                    afr[slot][mt], bfr[slot][i], acc[mt][i], 0, 0, 0);
        const int sn = (s + 2 < NKSTEP) ? (s + 2) : s;   // tail: harmless reload
        loadB(sn, slot);
        loadA(sn, slot);
    }

    // ---- epilogue: bias + LayerNorm from registers ----
    float gv[4], bv[4], lwv[4], biasv[4];
    #pragma unroll
    for (int i = 0; i < 4; ++i) {
        int col = wv * 64 + i * 16 + mrow;
        biasv[i] = bias[col];
        gv[i]    = gamma[col];
        bv[i]    = beta[col];
        if (DO_LINEAR) lwv[i] = lw[col];
    }
    #pragma unroll
    for (int mt = 0; mt < 2; ++mt)
        #pragma unroll
        for (int i = 0; i < 4; ++i)
            #pragma unroll
            for (int r = 0; r < 4; ++r)
                acc[mt][i][r] += biasv[i];

    // per-row partial sums over this wave's 64 cols
    #pragma unroll
    for (int mt = 0; mt < 2; ++mt)
        #pragma unroll
        for (int r = 0; r < 4; ++r) {
            float s  = acc[mt][0][r] + acc[mt][1][r] + acc[mt][2][r] + acc[mt][3][r];
            float sq = acc[mt][0][r] * acc[mt][0][r] + acc[mt][1][r] * acc[mt][1][r]
                     + acc[mt][2][r] * acc[mt][2][r] + acc[mt][3][r] * acc[mt][3][r];
            #pragma unroll
            for (int off = 1; off <= 8; off <<= 1) {
                s  += __shfl_xor(s,  off, 64);
                sq += __shfl_xor(sq, off, 64);
            }
            if (mrow == 0) red[mt * 16 + q * 4 + r][wv] = make_float2(s, sq);
        }
    __syncthreads();

    float muv[2][4], rsv[2][4];
    #pragma unroll
    for (int mt = 0; mt < 2; ++mt)
        #pragma unroll
        for (int r = 0; r < 4; ++r) {
            int row = mt * 16 + q * 4 + r;
            float2 p0 = red[row][0], p1 = red[row][1], p2 = red[row][2], p3 = red[row][3];
            float s  = p0.x + p1.x + p2.x + p3.x;
            float sq = p0.y + p1.y + p2.y + p3.y;
            float mu  = s * (1.f / 256.f);
            float var = sq * (1.f / 256.f) - mu * mu;
            muv[mt][r] = mu;
            rsv[mt][r] = rsqrtf(var + 1e-5f);
        }

    if (!DO_LINEAR) {
        // store relu(LN(h)) as bf16
        #pragma unroll
        for (int mt = 0; mt < 2; ++mt)
            #pragma unroll
            for (int r = 0; r < 4; ++r) {
                int l = l0 + mt * 16 + q * 4 + r;
                size_t base = ((size_t)b * Ln + l) * Fn;
                #pragma unroll
                for (int i = 0; i < 4; ++i) {
                    float o = fmaxf((acc[mt][i][r] - muv[mt][r]) * rsv[mt][r] * gv[i] + bv[i], 0.f);
                    hout[base + wv * 64 + i * 16 + mrow] = f2bf(o);
                }
            }
    } else {
        // fused linear head: dup = relu( relu(LN(h)) . lw + lb )
        #pragma unroll
        for (int mt = 0; mt < 2; ++mt)
            #pragma unroll
            for (int r = 0; r < 4; ++r) {
                float dot = 0.f;
                #pragma unroll
                for (int i = 0; i < 4; ++i) {
                    float o = fmaxf((acc[mt][i][r] - muv[mt][r]) * rsv[mt][r] * gv[i] + bv[i], 0.f);
                    dot += o * lwv[i];
                }
                #pragma unroll
                for (int off = 1; off <= 8; off <<= 1)
                    dot += __shfl_xor(dot, off, 64);
                if (mrow == 0) red2[mt * 16 + q * 4 + r][wv] = dot;
            }
        __syncthreads();
        if (t < MT) {
            float d = red2[t][0] + red2[t][1] + red2[t][2] + red2[t][3];
            dup[b * Ln + l0 + t] = fmaxf(d + lb[0], 0.f);
        }
    }
}

extern "C" void kernel_launch(void* const* d_in, const int* in_sizes, int n_in,
                              void* d_out, int out_size, void* d_ws, size_t ws_size,
                              hipStream_t stream) {
    const float* x    = (const float*)d_in[0];
    const int*   targ = (const int*)d_in[1];
    // d_in[2] = mel_max_length (scalar) = 2048, hardcoded
    const float* c1w = (const float*)d_in[3];
    const float* c1b = (const float*)d_in[4];
    const float* g1  = (const float*)d_in[5];
    const float* be1 = (const float*)d_in[6];
    const float* c2w = (const float*)d_in[7];
    const float* c2b = (const float*)d_in[8];
    const float* g2  = (const float*)d_in[9];
    const float* be2 = (const float*)d_in[10];
    const float* lw  = (const float*)d_in[11];
    const float* lb  = (const float*)d_in[12];

    float* out     = (float*)d_out;                       // (B,M,C)
    float* out_dup = out + (size_t)Bn * Mn * Cn;          // (B,L)

    // workspace layout (r0 layout: h1 global round-trip)
    char* ws = (char*)d_ws;
    unsigned short* bp1 = (unsigned short*)ws;                       // 384 KiB
    unsigned short* bp2 = (unsigned short*)(ws + 393216);            // 384 KiB
    unsigned short* h1  = (unsigned short*)(ws + 2 * 393216);        // 4 MiB bf16
    int*            map = (int*)(ws + 2 * 393216 + 4194304);         // 128 KiB

    // K1: weight pack (192 blocks) + duration scan (16 blocks)
    pack_scan<<<208, 256, 0, stream>>>(c1w, c2w, bp1, bp2, targ, map);

    // K2: conv1 (blocks 0..255) + gather first half (blocks 256..1279)
    conv_mfma<true, false, 0><<<NCONVBLK + NGHALF, 256, 0, stream>>>(
        (const void*)x, bp1, c1b, g1, be1, nullptr, nullptr, h1, nullptr,
        x, map, out);

    // K3: conv2 + fused linear head (blocks 0..255) + gather second half
    conv_mfma<false, true, 1048576><<<NCONVBLK + NGHALF, 256, 0, stream>>>(
        (const void*)h1, bp2, c2b, g2, be2, lw, lb, nullptr, out_dup,
        x, map, out);
}